// Round 8
// baseline (1285.471 us; speedup 1.0000x reference)
//
#include <hip/hip_runtime.h>
#include <hip/hip_bf16.h>

// Problem constants (from the reference)
#define N_NODES 20000
#define F_DIM   512
#define H_DIM   128
#define C_DIM   64
#define E_EDGES 640000

// ---------------- workspace layout (float offsets from d_ws) ----------------
// flag: int at word 0 (1 = inputs are f32, 0 = inputs are bf16)
#define P_WV1   64                      // 9 floats
#define P_B1    80                      // 384 floats
#define P_WV2   464                     // 9
#define P_B2    480                     // 192 -> ends 672
#define P_E     1024                    // fp32 path: 3*N*H f32 | bf16 path: Er tables (bf16)
#define P_H     (P_E + 3*N_NODES*H_DIM) // fp32 path: 3*N*H f32 | bf16 path: h tables (bf16)
#define P_YSUM  (P_H + 3*N_NODES*H_DIM) // N*C f32 (both paths)
// CSR region: 3 adjacencies, each {rowptr[20032 ints], packed edges int2[E]}
// Edges within each row are written in dst-BUCKET order (bucket = dst>>12) so
// concurrently-running waves sweep dst-space together -> gather window stays
// L2-resident (r7 counters: 419MB L2-miss traffic vs ~45MB compulsory).
#define RP_SZ      20032
#define CSR_STRIDE (RP_SZ + 2*E_EDGES)          // in 4-byte words (unchanged)
#define P_CSR   (P_YSUM + N_NODES*C_DIM)
#define P_CUR   (P_CSR + 3*CSR_STRIDE)          // legacy scratch (unused now)
// bf16-path pre-transposed weights: inside P_E slack (bf16 Eb tables use
// <= 3.84M of the 7.68M words). Lifetimes flag-disjoint from fp32 path.
#define P_WT1   (P_E + 4000000)                 // 9*128*512 bf16 = 294912 words
#define P_WT2   (P_E + 4300000)                 // 9*64*128 bf16  = 36864 words
// fp32-path split weights (hi/lo bf16, k-major):
//  W1 pair in P_YSUM (free until layer-2 combine; 589824 <= 1.28M words)
//  W2 pair in P_E+4.0M, written BETWEEN layers (L1 Er dead, L2 Er <= 3.84M)
#define P_W1H   (P_YSUM)
#define P_W1L   (P_YSUM + 294912)
#define P_W2H   (P_E + 4000000)
#define P_W2L   (P_E + 4050000)
// CSR-build scratch: (src,bucket) histogram->scan (in place) + cursors.
// 2 x 3 x 160000 ints = 960000 words, lives in P_YSUM (1.28M words), which is
// dead during the build (W1 split + ysum writes come after, stream-ordered).
#define NBUCK       8                           // 5 used (dst>>12, dst<20000)
#define BUCK_SHIFT  12
#define B2_STRIDE   (N_NODES * NBUCK)           // 160000
// total footprint unchanged at ~20.56M words = 82.2 MB (harness-verified)

typedef __attribute__((ext_vector_type(8))) unsigned short u16x8;
typedef __attribute__((ext_vector_type(8))) __bf16 bf16x8;
typedef __attribute__((ext_vector_type(4))) float f32x4;

__device__ inline float cvt(float x) { return x; }
__device__ inline float cvt(__hip_bfloat16 x) { return __bfloat162float(x); }

__device__ inline void store_out(float v, float* p) { *p = v; }
__device__ inline void store_out(float v, __hip_bfloat16* p) { *p = __float2bfloat16(v); }

__device__ inline unsigned short f2bf_bits(float x) {
    __hip_bfloat16 b = __float2bfloat16(x);
    return *(unsigned short*)&b;
}
// split fp32 -> (hi, lo) bf16 pair: x ~= hi + lo, |x-(hi+lo)| ~ 2^-17 |x|
__device__ inline void splitbf(float x, unsigned short& h, unsigned short& l) {
    h = f2bf_bits(x);
    float hf = __uint_as_float(((unsigned int)h) << 16);
    l = f2bf_bits(x - hf);
}

// ---------------- dtype probe ----------------
__global__ void detect_kernel(const unsigned short* __restrict__ x, int* flag) {
    __shared__ int cnt;
    if (threadIdx.x == 0) cnt = 0;
    __syncthreads();
    int c = 0;
    for (int i = threadIdx.x; i < 4096; i += 256) {
        int ex = (x[i] >> 7) & 0xff;
        if (ex >= 140) c++;
    }
    atomicAdd(&cnt, c);
    __syncthreads();
    if (threadIdx.x == 0) *flag = (cnt > 64) ? 1 : 0;
}

// Convert the small params (wv1,b1,wv2,b2) to fp32 in ws.
__global__ void prep_kernel(const int* __restrict__ flag,
                            const void* wv1, const void* b1,
                            const void* wv2, const void* b2, float* ws) {
    bool f32 = (*flag == 1);
    int t = threadIdx.x;
    auto get = [&](const void* p, int i) -> float {
        return f32 ? ((const float*)p)[i]
                   : __bfloat162float(((const __hip_bfloat16*)p)[i]);
    };
    if (t < 9) ws[P_WV1 + t] = get(wv1, t);
    if (t < 9) ws[P_WV2 + t] = get(wv2, t);
    for (int i = t; i < 3*H_DIM; i += 256) ws[P_B1 + i] = get(b1, i);
    for (int i = t; i < 3*C_DIM; i += 256) ws[P_B2 + i] = get(b2, i);
}

// ---------------- CSR build (batched, dst-bucket-ordered rows) --------------
// histogram over (src, dst-bucket)
__global__ __launch_bounds__(256)
void hist2_kernel(const int* __restrict__ s0, const int* __restrict__ d0,
                  const int* __restrict__ s1, const int* __restrict__ d1,
                  const int* __restrict__ s2, const int* __restrict__ d2,
                  int* __restrict__ deg2) {
    int e = blockIdx.x * 256 + threadIdx.x;
    if (e >= E_EDGES) return;
    const int z = blockIdx.y;
    const int* src = (z == 0) ? s0 : (z == 1) ? s1 : s2;
    const int* dst = (z == 0) ? d0 : (z == 1) ? d1 : d2;
    int idx = src[e] * NBUCK + (dst[e] >> BUCK_SHIFT);
    atomicAdd(&deg2[z * B2_STRIDE + idx], 1);
}

// 3 blocks: in-place exclusive scan of deg2[(src,bucket)] -> start positions;
// every NBUCK-th entry is the per-node rowptr, written to the persistent rp.
__global__ __launch_bounds__(256)
void scan3b_kernel(int* __restrict__ deg2, int* __restrict__ rpBase) {
    __shared__ int sums[256];
    int* d = deg2 + blockIdx.x * B2_STRIDE;
    int* rowptr = rpBase + (long)blockIdx.x * CSR_STRIDE;
    const int CHUNK = B2_STRIDE / 256;          // 625, exact
    int t = threadIdx.x;
    int beg = t * CHUNK, end = beg + CHUNK;
    int s = 0;
    for (int i = beg; i < end; ++i) s += d[i];
    sums[t] = s;
    __syncthreads();
    for (int off = 1; off < 256; off <<= 1) {
        int v = (t >= off) ? sums[t - off] : 0;
        __syncthreads();
        sums[t] += v;
        __syncthreads();
    }
    int run = sums[t] - s;                      // exclusive prefix of this chunk
    for (int i = beg; i < end; ++i) {
        int v = d[i];
        d[i] = run;                             // in-place: start of (src,bucket)
        if ((i & (NBUCK - 1)) == 0) rowptr[i >> 3] = run;  // node start
        run += v;
    }
    if (t == 255) rowptr[N_NODES] = run;
}

// one launch fills all 3 CSRs; val dtype chosen by flag at runtime.
// Position = (src,bucket) start + cursor -> rows end up dst-bucket-sorted.
__global__ __launch_bounds__(256)
void fill3_kernel(const int* __restrict__ flag,
                  const int* __restrict__ s0, const int* __restrict__ d0,
                  const void* __restrict__ v0,
                  const int* __restrict__ s1, const int* __restrict__ d1,
                  const void* __restrict__ v1,
                  const int* __restrict__ s2, const int* __restrict__ d2,
                  const void* __restrict__ v2,
                  const int* __restrict__ deg2, int* __restrict__ cur2,
                  int* __restrict__ rpBase) {
    int e = blockIdx.x * 256 + threadIdx.x;
    if (e >= E_EDGES) return;
    const int z = blockIdx.y;
    const int* src = (z == 0) ? s0 : (z == 1) ? s1 : s2;
    const int* dst = (z == 0) ? d0 : (z == 1) ? d1 : d2;
    const void* val = (z == 0) ? v0 : (z == 1) ? v1 : v2;
    float v = (*flag == 1) ? ((const float*)val)[e]
                           : __bfloat162float(((const __hip_bfloat16*)val)[e]);
    int d = dst[e];
    int idx = z * B2_STRIDE + src[e] * NBUCK + (d >> BUCK_SHIFT);
    int pos = deg2[idx] + atomicAdd(&cur2[idx], 1);
    int2* ed = (int2*)(rpBase + (long)z * CSR_STRIDE + RP_SZ);
    ed[pos] = make_int2(d, __float_as_int(v));
}

// ---------------- weight transpose (bf16 path) ----------------
// W [z][K][HO] bf16  ->  Wt [z][HO][K] bf16
__global__ __launch_bounds__(256)
void transpose_w_kernel(const int* __restrict__ flag,
                        const void* __restrict__ Wsrc,
                        unsigned short* __restrict__ Wt, int K, int HO) {
    if (*flag != 0) return;
    __shared__ unsigned short T[64][80];        // pad 80: 16B-aligned vec rows
    const unsigned short* W = (const unsigned short*)Wsrc + (long)blockIdx.z * K * HO;
    unsigned short* O = Wt + (long)blockIdx.z * HO * K;
    const int k0 = blockIdx.x * 64, n0 = blockIdx.y * 64;
    const int t = threadIdx.x;
    const int rr = t >> 3, cc = (t & 7) * 8;
    #pragma unroll
    for (int i = 0; i < 2; ++i) {
        int k = rr + i * 32;
        *(u16x8*)&T[k][cc] = *(const u16x8*)&W[(long)(k0 + k) * HO + n0 + cc];
    }
    __syncthreads();
    #pragma unroll
    for (int i = 0; i < 2; ++i) {
        int nn = rr + i * 32;
        u16x8 v;
        #pragma unroll
        for (int j = 0; j < 8; ++j) v[j] = T[cc + j][nn];
        *(u16x8*)&O[(long)(n0 + nn) * K + k0 + cc] = v;
    }
}

// ---------------- weight transpose + hi/lo split (fp32 path) ----------------
// W [z][K][HO] f32 -> Wh/Wl [z][HO][K] bf16
__global__ __launch_bounds__(256)
void split_w_kernel(const int* __restrict__ flag,
                    const float* __restrict__ Wsrc,
                    unsigned short* __restrict__ Wh,
                    unsigned short* __restrict__ Wl, int K, int HO) {
    if (*flag != 1) return;
    __shared__ float T[64][68];
    const float* W = Wsrc + (long)blockIdx.z * K * HO;
    unsigned short* Oh = Wh + (long)blockIdx.z * HO * K;
    unsigned short* Ol = Wl + (long)blockIdx.z * HO * K;
    const int k0 = blockIdx.x * 64, n0 = blockIdx.y * 64;
    const int t = threadIdx.x;
    #pragma unroll
    for (int i = 0; i < 16; ++i) {
        int idx = t + i * 256;
        int r = idx >> 6, c = idx & 63;
        T[r][c] = W[(long)(k0 + r) * HO + n0 + c];
    }
    __syncthreads();
    #pragma unroll
    for (int i = 0; i < 16; ++i) {
        int idx = t + i * 256;
        int nn = idx >> 6, kk = idx & 63;
        unsigned short h, l;
        splitbf(T[kk][nn], h, l);
        Oh[(long)(n0 + nn) * K + k0 + kk] = h;
        Ol[(long)(n0 + nn) * K + k0 + kk] = l;
    }
}

// ---------------- MFMA GEMM layer 1 (bf16): out[N,128]bf16 = X[N,512] @ W ----
#define SWZ(r, kb) (((r) << 7) + ((kb) ^ (((r) & 7) << 4)))

__global__ __launch_bounds__(256)
void gemm_mfma1_kernel(const int* __restrict__ flag,
                       const unsigned short* __restrict__ x0,
                       const unsigned short* __restrict__ x1,
                       const unsigned short* __restrict__ x2,
                       const unsigned short* __restrict__ WtBase,
                       unsigned short* __restrict__ outBase, int n) {
    if (*flag != 0) return;
    const int role = blockIdx.y;
    const unsigned short* X = (role == 0) ? x0 : (role == 1) ? x1 : x2;
    const unsigned short* Wt = WtBase + (long)role * H_DIM * F_DIM;
    unsigned short* out = outBase + (long)role * N_NODES * H_DIM;
    __shared__ __align__(16) unsigned short As[64 * 64];
    __shared__ __align__(16) unsigned short Bs[128 * 64];
    const int t = threadIdx.x;
    const int lane = t & 63;
    const int wave = t >> 6;
    const int wm = wave & 1, wn = wave >> 1;
    const int row0 = blockIdx.x * 64;
    const int rl = lane & 15;
    const int kq = lane >> 4;                   // 0..3
    const int sr = t >> 3;                      // staging row (0..31)
    const int sc = (t & 7) * 8;                 // staging k offset (elements)
    f32x4 acc[2][4] = {};
    for (int k0 = 0; k0 < F_DIM; k0 += 64) {
        #pragma unroll
        for (int i = 0; i < 2; ++i) {           // A: 64 rows x 64 k
            int r = i * 32 + sr;
            int gr = row0 + r; if (gr >= n) gr = n - 1;   // clamp, store-guarded
            u16x8 v = *(const u16x8*)&X[(long)gr * F_DIM + k0 + sc];
            *(u16x8*)((char*)As + SWZ(r, sc * 2)) = v;
        }
        #pragma unroll
        for (int i = 0; i < 4; ++i) {           // B: 128 n-rows x 64 k
            int r = i * 32 + sr;
            u16x8 v = *(const u16x8*)&Wt[(long)r * F_DIM + k0 + sc];
            *(u16x8*)((char*)Bs + SWZ(r, sc * 2)) = v;
        }
        __syncthreads();
        #pragma unroll
        for (int s = 0; s < 2; ++s) {           // two K=32 sub-steps
            const int kb = s * 64 + kq * 16;    // lane's 16B within the row
            bf16x8 af[2], bfr[4];
            #pragma unroll
            for (int mi = 0; mi < 2; ++mi) {
                int r = wm * 32 + mi * 16 + rl;
                af[mi] = *(const bf16x8*)((const char*)As + SWZ(r, kb));
            }
            #pragma unroll
            for (int ni = 0; ni < 4; ++ni) {
                int r = wn * 64 + ni * 16 + rl;
                bfr[ni] = *(const bf16x8*)((const char*)Bs + SWZ(r, kb));
            }
            #pragma unroll
            for (int mi = 0; mi < 2; ++mi)
                #pragma unroll
                for (int ni = 0; ni < 4; ++ni)
                    acc[mi][ni] = __builtin_amdgcn_mfma_f32_16x16x32_bf16(
                        af[mi], bfr[ni], acc[mi][ni], 0, 0, 0);
        }
        __syncthreads();
    }
    #pragma unroll
    for (int mi = 0; mi < 2; ++mi) {
        #pragma unroll
        for (int q = 0; q < 4; ++q) {
            int row = row0 + wm * 32 + mi * 16 + kq * 4 + q;
            if (row < n) {
                #pragma unroll
                for (int ni = 0; ni < 4; ++ni) {
                    int col = wn * 64 + ni * 16 + rl;
                    out[(long)row * H_DIM + col] = f2bf_bits(acc[mi][ni][q]);
                }
            }
        }
    }
}

// ---------------- MFMA GEMM layer 1 (fp32 path, split-bf16 3-product) -------
__global__ __launch_bounds__(256)
void gemm_mfma1f_kernel(const int* __restrict__ flag,
                        const float* __restrict__ x0,
                        const float* __restrict__ x1,
                        const float* __restrict__ x2,
                        const unsigned short* __restrict__ WhBase,
                        const unsigned short* __restrict__ WlBase,
                        float* __restrict__ outBase, int n) {
    if (*flag != 1) return;
    const int role = blockIdx.y;
    const float* X = (role == 0) ? x0 : (role == 1) ? x1 : x2;
    const unsigned short* Wh = WhBase + (long)role * H_DIM * F_DIM;
    const unsigned short* Wl = WlBase + (long)role * H_DIM * F_DIM;
    float* out = outBase + (long)role * N_NODES * H_DIM;
    __shared__ __align__(16) unsigned short Ash[64 * 64];
    __shared__ __align__(16) unsigned short Asl[64 * 64];
    __shared__ __align__(16) unsigned short Bsh[128 * 64];
    __shared__ __align__(16) unsigned short Bsl[128 * 64];
    const int t = threadIdx.x;
    const int lane = t & 63;
    const int wave = t >> 6;
    const int wm = wave & 1, wn = wave >> 1;
    const int row0 = blockIdx.x * 64;
    const int rl = lane & 15;
    const int kq = lane >> 4;
    const int sr = t >> 3;
    const int sc = (t & 7) * 8;
    f32x4 acc[2][4] = {};
    for (int k0 = 0; k0 < F_DIM; k0 += 64) {
        #pragma unroll
        for (int i = 0; i < 2; ++i) {           // A: 64 rows x 64 k, split on the fly
            int r = i * 32 + sr;
            int gr = row0 + r; if (gr >= n) gr = n - 1;
            float4 v0 = *(const float4*)&X[(long)gr * F_DIM + k0 + sc];
            float4 v1 = *(const float4*)&X[(long)gr * F_DIM + k0 + sc + 4];
            float xs[8] = {v0.x, v0.y, v0.z, v0.w, v1.x, v1.y, v1.z, v1.w};
            u16x8 hi, lo;
            #pragma unroll
            for (int j = 0; j < 8; ++j) { unsigned short h, l; splitbf(xs[j], h, l); hi[j] = h; lo[j] = l; }
            *(u16x8*)((char*)Ash + SWZ(r, sc * 2)) = hi;
            *(u16x8*)((char*)Asl + SWZ(r, sc * 2)) = lo;
        }
        #pragma unroll
        for (int i = 0; i < 4; ++i) {           // B: 128 n-rows x 64 k (pre-split)
            int r = i * 32 + sr;
            u16x8 vh = *(const u16x8*)&Wh[(long)r * F_DIM + k0 + sc];
            u16x8 vl = *(const u16x8*)&Wl[(long)r * F_DIM + k0 + sc];
            *(u16x8*)((char*)Bsh + SWZ(r, sc * 2)) = vh;
            *(u16x8*)((char*)Bsl + SWZ(r, sc * 2)) = vl;
        }
        __syncthreads();
        #pragma unroll
        for (int s = 0; s < 2; ++s) {
            const int kb = s * 64 + kq * 16;
            bf16x8 ah[2], al[2], bh[4], bl[4];
            #pragma unroll
            for (int mi = 0; mi < 2; ++mi) {
                int r = wm * 32 + mi * 16 + rl;
                ah[mi] = *(const bf16x8*)((const char*)Ash + SWZ(r, kb));
                al[mi] = *(const bf16x8*)((const char*)Asl + SWZ(r, kb));
            }
            #pragma unroll
            for (int ni = 0; ni < 4; ++ni) {
                int r = wn * 64 + ni * 16 + rl;
                bh[ni] = *(const bf16x8*)((const char*)Bsh + SWZ(r, kb));
                bl[ni] = *(const bf16x8*)((const char*)Bsl + SWZ(r, kb));
            }
            #pragma unroll
            for (int mi = 0; mi < 2; ++mi)
                #pragma unroll
                for (int ni = 0; ni < 4; ++ni) {
                    acc[mi][ni] = __builtin_amdgcn_mfma_f32_16x16x32_bf16(
                        ah[mi], bh[ni], acc[mi][ni], 0, 0, 0);
                    acc[mi][ni] = __builtin_amdgcn_mfma_f32_16x16x32_bf16(
                        ah[mi], bl[ni], acc[mi][ni], 0, 0, 0);
                    acc[mi][ni] = __builtin_amdgcn_mfma_f32_16x16x32_bf16(
                        al[mi], bh[ni], acc[mi][ni], 0, 0, 0);
                }
        }
        __syncthreads();
    }
    #pragma unroll
    for (int mi = 0; mi < 2; ++mi) {
        #pragma unroll
        for (int q = 0; q < 4; ++q) {
            int row = row0 + wm * 32 + mi * 16 + kq * 4 + q;
            if (row < n) {
                #pragma unroll
                for (int ni = 0; ni < 4; ++ni) {
                    int col = wn * 64 + ni * 16 + rl;
                    out[(long)row * H_DIM + col] = acc[mi][ni][q];
                }
            }
        }
    }
}

// ---------------- MFMA GEMM layer 2 (bf16): out[N,64]bf16 = h[N,128] @ W2 ----
#define SWZ2(r, kb) (((r) << 8) + ((kb) ^ (((r) & 7) << 4)))

__global__ __launch_bounds__(256)
void gemm_mfma2_kernel(const int* __restrict__ flag,
                       const unsigned short* __restrict__ h0,
                       const unsigned short* __restrict__ h1,
                       const unsigned short* __restrict__ h2,
                       const unsigned short* __restrict__ WtBase,
                       unsigned short* __restrict__ outBase, int n) {
    if (*flag != 0) return;
    const int role = blockIdx.y;
    const unsigned short* X = (role == 0) ? h0 : (role == 1) ? h1 : h2;
    const unsigned short* Wt = WtBase + (long)role * C_DIM * H_DIM;
    unsigned short* out = outBase + (long)role * N_NODES * C_DIM;
    __shared__ __align__(16) unsigned short As[64 * 128];
    __shared__ __align__(16) unsigned short Bs[64 * 128];
    const int t = threadIdx.x;
    const int lane = t & 63;
    const int wave = t >> 6;
    const int wm = wave & 1, wn = wave >> 1;
    const int row0 = blockIdx.x * 64;
    const int rl = lane & 15;
    const int kq = lane >> 4;
    #pragma unroll
    for (int i = 0; i < 4; ++i) {
        int e = t + i * 256;
        int r = e >> 4, c8 = e & 15;
        int gr = row0 + r; if (gr >= n) gr = n - 1;
        u16x8 va = *(const u16x8*)&X[(long)gr * H_DIM + c8 * 8];
        *(u16x8*)((char*)As + SWZ2(r, c8 * 16)) = va;
        u16x8 vb = *(const u16x8*)&Wt[(long)r * H_DIM + c8 * 8];
        *(u16x8*)((char*)Bs + SWZ2(r, c8 * 16)) = vb;
    }
    __syncthreads();
    f32x4 acc[2][2] = {};
    #pragma unroll
    for (int s = 0; s < 4; ++s) {
        const int kb = s * 64 + kq * 16;
        bf16x8 af[2], bfr[2];
        #pragma unroll
        for (int mi = 0; mi < 2; ++mi) {
            int r = wm * 32 + mi * 16 + rl;
            af[mi] = *(const bf16x8*)((const char*)As + SWZ2(r, kb));
        }
        #pragma unroll
        for (int ni = 0; ni < 2; ++ni) {
            int r = wn * 32 + ni * 16 + rl;
            bfr[ni] = *(const bf16x8*)((const char*)Bs + SWZ2(r, kb));
        }
        #pragma unroll
        for (int mi = 0; mi < 2; ++mi)
            #pragma unroll
            for (int ni = 0; ni < 2; ++ni)
                acc[mi][ni] = __builtin_amdgcn_mfma_f32_16x16x32_bf16(
                    af[mi], bfr[ni], acc[mi][ni], 0, 0, 0);
    }
    #pragma unroll
    for (int mi = 0; mi < 2; ++mi) {
        #pragma unroll
        for (int q = 0; q < 4; ++q) {
            int row = row0 + wm * 32 + mi * 16 + kq * 4 + q;
            if (row < n) {
                #pragma unroll
                for (int ni = 0; ni < 2; ++ni) {
                    int col = wn * 32 + ni * 16 + rl;
                    out[(long)row * C_DIM + col] = f2bf_bits(acc[mi][ni][q]);
                }
            }
        }
    }
}

// ---------------- MFMA GEMM layer 2 (fp32 path, split-bf16 3-product) -------
__global__ __launch_bounds__(256)
void gemm_mfma2f_kernel(const int* __restrict__ flag,
                        const float* __restrict__ h0,
                        const float* __restrict__ h1,
                        const float* __restrict__ h2,
                        const unsigned short* __restrict__ WhBase,
                        const unsigned short* __restrict__ WlBase,
                        float* __restrict__ outBase, int n) {
    if (*flag != 1) return;
    const int role = blockIdx.y;
    const float* X = (role == 0) ? h0 : (role == 1) ? h1 : h2;
    const unsigned short* Wh = WhBase + (long)role * C_DIM * H_DIM;
    const unsigned short* Wl = WlBase + (long)role * C_DIM * H_DIM;
    float* out = outBase + (long)role * N_NODES * C_DIM;
    __shared__ __align__(16) unsigned short Ash[64 * 128];
    __shared__ __align__(16) unsigned short Asl[64 * 128];
    __shared__ __align__(16) unsigned short Bsh[64 * 128];
    __shared__ __align__(16) unsigned short Bsl[64 * 128];
    const int t = threadIdx.x;
    const int lane = t & 63;
    const int wave = t >> 6;
    const int wm = wave & 1, wn = wave >> 1;
    const int row0 = blockIdx.x * 64;
    const int rl = lane & 15;
    const int kq = lane >> 4;
    #pragma unroll
    for (int i = 0; i < 4; ++i) {
        int e = t + i * 256;
        int r = e >> 4, c8 = e & 15;
        int gr = row0 + r; if (gr >= n) gr = n - 1;
        float4 v0 = *(const float4*)&X[(long)gr * H_DIM + c8 * 8];
        float4 v1 = *(const float4*)&X[(long)gr * H_DIM + c8 * 8 + 4];
        float xs[8] = {v0.x, v0.y, v0.z, v0.w, v1.x, v1.y, v1.z, v1.w};
        u16x8 hi, lo;
        #pragma unroll
        for (int j = 0; j < 8; ++j) { unsigned short h, l; splitbf(xs[j], h, l); hi[j] = h; lo[j] = l; }
        *(u16x8*)((char*)Ash + SWZ2(r, c8 * 16)) = hi;
        *(u16x8*)((char*)Asl + SWZ2(r, c8 * 16)) = lo;
        u16x8 vh = *(const u16x8*)&Wh[(long)r * H_DIM + c8 * 8];
        u16x8 vl = *(const u16x8*)&Wl[(long)r * H_DIM + c8 * 8];
        *(u16x8*)((char*)Bsh + SWZ2(r, c8 * 16)) = vh;
        *(u16x8*)((char*)Bsl + SWZ2(r, c8 * 16)) = vl;
    }
    __syncthreads();
    f32x4 acc[2][2] = {};
    #pragma unroll
    for (int s = 0; s < 4; ++s) {
        const int kb = s * 64 + kq * 16;
        bf16x8 ah[2], al[2], bh[2], bl[2];
        #pragma unroll
        for (int mi = 0; mi < 2; ++mi) {
            int r = wm * 32 + mi * 16 + rl;
            ah[mi] = *(const bf16x8*)((const char*)Ash + SWZ2(r, kb));
            al[mi] = *(const bf16x8*)((const char*)Asl + SWZ2(r, kb));
        }
        #pragma unroll
        for (int ni = 0; ni < 2; ++ni) {
            int r = wn * 32 + ni * 16 + rl;
            bh[ni] = *(const bf16x8*)((const char*)Bsh + SWZ2(r, kb));
            bl[ni] = *(const bf16x8*)((const char*)Bsl + SWZ2(r, kb));
        }
        #pragma unroll
        for (int mi = 0; mi < 2; ++mi)
            #pragma unroll
            for (int ni = 0; ni < 2; ++ni) {
                acc[mi][ni] = __builtin_amdgcn_mfma_f32_16x16x32_bf16(
                    ah[mi], bh[ni], acc[mi][ni], 0, 0, 0);
                acc[mi][ni] = __builtin_amdgcn_mfma_f32_16x16x32_bf16(
                    ah[mi], bl[ni], acc[mi][ni], 0, 0, 0);
                acc[mi][ni] = __builtin_amdgcn_mfma_f32_16x16x32_bf16(
                    al[mi], bh[ni], acc[mi][ni], 0, 0, 0);
            }
    }
    #pragma unroll
    for (int mi = 0; mi < 2; ++mi) {
        #pragma unroll
        for (int q = 0; q < 4; ++q) {
            int row = row0 + wm * 32 + mi * 16 + kq * 4 + q;
            if (row < n) {
                #pragma unroll
                for (int ni = 0; ni < 2; ++ni) {
                    int col = wn * 32 + ni * 16 + rl;
                    out[(long)row * C_DIM + col] = acc[mi][ni][q];
                }
            }
        }
    }
}

// ---------------- fused CSR SpMM, fp32 tables (fp32 path), packed edges -----
template <int FP, bool ACCUM>
__global__ __launch_bounds__(256)
void spmm_f32_kernel(const int* __restrict__ flag,
                     const int* __restrict__ rp0, const int2* __restrict__ ed0,
                     const int* __restrict__ rp1, const int2* __restrict__ ed1,
                     const int* __restrict__ rp2, const int2* __restrict__ ed2,
                     const float* __restrict__ Et0, const float* __restrict__ Et1,
                     const float* __restrict__ Et2,
                     const float* __restrict__ wvp, const float* __restrict__ bias,
                     float* __restrict__ out) {
    if (*flag != 1) return;
    constexpr int HO = FP * 64;
    const int node = blockIdx.x * 4 + (threadIdx.x >> 6);
    const int lane = threadIdx.x & 63;
    const int fbase = lane * FP;
    float acc[FP];
    #pragma unroll
    for (int k = 0; k < FP; ++k) acc[k] = 0.f;

    const int*  rps[3] = {rp0, rp1, rp2};
    const int2* eds[3] = {ed0, ed1, ed2};
    const float* Ets[3] = {Et0, Et1, Et2};
    #pragma unroll
    for (int r = 0; r < 3; ++r) {
        const float s = 1.01f * wvp[r];
        const int2* ed = eds[r];
        const float* Et = Ets[r] + fbase;
        int e = rps[r][node];
        const int end = rps[r][node + 1];
        // 8 independent gathers in flight
        for (; e + 8 <= end; e += 8) {
            int2 E[8]; float vv[8]; const float* rr[8];
            #pragma unroll
            for (int q = 0; q < 8; ++q) E[q] = ed[e + q];
            #pragma unroll
            for (int q = 0; q < 8; ++q) {
                vv[q] = s * __int_as_float(E[q].y);
                rr[q] = Et + (long)E[q].x * HO;
            }
            #pragma unroll
            for (int q = 0; q < 8; ++q)
                #pragma unroll
                for (int k = 0; k < FP; ++k) acc[k] += vv[q] * rr[q][k];
        }
        for (; e + 2 <= end; e += 2) {
            int2 E0 = ed[e], E1 = ed[e + 1];
            float v0 = s * __int_as_float(E0.y), v1 = s * __int_as_float(E1.y);
            const float* r0 = Et + (long)E0.x * HO;
            const float* r1 = Et + (long)E1.x * HO;
            #pragma unroll
            for (int k = 0; k < FP; ++k) acc[k] += v0 * r0[k];
            #pragma unroll
            for (int k = 0; k < FP; ++k) acc[k] += v1 * r1[k];
        }
        if (e < end) {
            int2 E0 = ed[e];
            float v0 = s * __int_as_float(E0.y);
            const float* r0 = Et + (long)E0.x * HO;
            #pragma unroll
            for (int k = 0; k < FP; ++k) acc[k] += v0 * r0[k];
        }
    }
    const float* e0 = Et0 + (long)node * HO + fbase;
    const float* bp = bias + fbase;
    float* o = out + (long)node * HO + fbase;
    #pragma unroll
    for (int k = 0; k < FP; ++k) {
        float x = e0[k] + acc[k] + bp[k];
        x = x > 0.f ? x : 0.f;
        if (ACCUM) o[k] += x; else o[k] = x;
    }
}

// ---------------- fused CSR SpMM, bf16 tables (bf16 path), packed edges -----
template <int HO, bool ACCUM, bool OUT_BF16>
__global__ __launch_bounds__(256)
void spmm_bf16_kernel(const int* __restrict__ flag,
                      const int* __restrict__ rp0, const int2* __restrict__ ed0,
                      const int* __restrict__ rp1, const int2* __restrict__ ed1,
                      const int* __restrict__ rp2, const int2* __restrict__ ed2,
                      const unsigned short* __restrict__ Et0,
                      const unsigned short* __restrict__ Et1,
                      const unsigned short* __restrict__ Et2,
                      const float* __restrict__ wvp, const float* __restrict__ bias,
                      void* __restrict__ outp) {
    if (*flag != 0) return;
    constexpr int NL = HO / 2;                  // lanes per node
    constexpr int NPW = 64 / NL;                // nodes per wave
    const int t = threadIdx.x;
    const int lane = t & 63;
    const int li = lane % NL;
    const int node = blockIdx.x * (4 * NPW) + (t >> 6) * NPW + lane / NL;
    const int fl = li * 2;
    float a0 = 0.f, a1 = 0.f;

    const int*  rps[3] = {rp0, rp1, rp2};
    const int2* eds[3] = {ed0, ed1, ed2};
    const unsigned int* Ets[3] = {(const unsigned int*)Et0,
                                  (const unsigned int*)Et1,
                                  (const unsigned int*)Et2};
    #pragma unroll
    for (int r = 0; r < 3; ++r) {
        const float s = 1.01f * wvp[r];
        const int2* ed = eds[r];
        const unsigned int* Et = Ets[r] + li;   // word index: d*NL + li
        int e = rps[r][node];
        const int end = rps[r][node + 1];
        for (; e + 4 <= end; e += 4) {
            int2 E0 = ed[e], E1 = ed[e + 1], E2 = ed[e + 2], E3 = ed[e + 3];
            float v0 = s * __int_as_float(E0.y), v1 = s * __int_as_float(E1.y);
            float v2 = s * __int_as_float(E2.y), v3 = s * __int_as_float(E3.y);
            unsigned int w0 = Et[(long)E0.x * NL];
            unsigned int w1 = Et[(long)E1.x * NL];
            unsigned int w2 = Et[(long)E2.x * NL];
            unsigned int w3 = Et[(long)E3.x * NL];
            a0 += v0 * __uint_as_float(w0 << 16);
            a1 += v0 * __uint_as_float(w0 & 0xffff0000u);
            a0 += v1 * __uint_as_float(w1 << 16);
            a1 += v1 * __uint_as_float(w1 & 0xffff0000u);
            a0 += v2 * __uint_as_float(w2 << 16);
            a1 += v2 * __uint_as_float(w2 & 0xffff0000u);
            a0 += v3 * __uint_as_float(w3 << 16);
            a1 += v3 * __uint_as_float(w3 & 0xffff0000u);
        }
        for (; e < end; ++e) {
            int2 E0 = ed[e];
            float v0 = s * __int_as_float(E0.y);
            unsigned int w0 = Et[(long)E0.x * NL];
            a0 += v0 * __uint_as_float(w0 << 16);
            a1 += v0 * __uint_as_float(w0 & 0xffff0000u);
        }
    }
    unsigned int ws0 = ((const unsigned int*)Et0)[(long)node * NL + li];
    float x0 = __uint_as_float(ws0 << 16)        + a0 + bias[fl];
    float x1 = __uint_as_float(ws0 & 0xffff0000u) + a1 + bias[fl + 1];
    x0 = x0 > 0.f ? x0 : 0.f;
    x1 = x1 > 0.f ? x1 : 0.f;
    if (OUT_BF16) {
        unsigned int packed = ((unsigned int)f2bf_bits(x1) << 16) | f2bf_bits(x0);
        ((unsigned int*)outp)[(long)node * NL + li] = packed;
    } else {
        float* o = (float*)outp + (long)node * HO + fl;
        if (ACCUM) { o[0] += x0; o[1] += x1; }
        else       { o[0] = x0;  o[1] = x1; }
    }
}

template <typename TOUT>
__global__ __launch_bounds__(256)
void final_kernel(const int* __restrict__ flag, int want,
                  const float* __restrict__ ysum, TOUT* __restrict__ out, int n) {
    if (*flag != want) return;
    int i = blockIdx.x * 256 + threadIdx.x;
    if (i >= n) return;
    store_out(fabsf(ysum[i] * (1.f / 3.f)), &out[i]);
}

extern "C" void kernel_launch(void* const* d_in, const int* in_sizes, int n_in,
                              void* d_out, int out_size, void* d_ws, size_t ws_size,
                              hipStream_t stream) {
    float* ws = (float*)d_ws;
    int* flag = (int*)d_ws;
    static const int perm[3][3] = {{0, 1, 2}, {1, 0, 2}, {2, 0, 1}};

    detect_kernel<<<1, 256, 0, stream>>>((const unsigned short*)d_in[0], flag);
    prep_kernel<<<1, 256, 0, stream>>>(flag, d_in[13], d_in[14], d_in[16], d_in[17], ws);

    // ---------------- CSR build (bucket-ordered; scratch in dead P_YSUM) ----
    int* csrbase = (int*)(ws + P_CSR);
    int* rp[3]; int2* ed[3];
    for (int j = 0; j < 3; ++j) {
        rp[j] = csrbase + (long)j * CSR_STRIDE;
        ed[j] = (int2*)(rp[j] + RP_SZ);
    }
    {
        int* deg2 = (int*)(ws + P_YSUM);                // 3 x 160000
        int* cur2 = deg2 + 3 * B2_STRIDE;               // 3 x 160000
        hipMemsetAsync(deg2, 0, (size_t)6 * B2_STRIDE * 4, stream);
        dim3 ge((E_EDGES + 255) / 256, 3);
        hist2_kernel<<<ge, 256, 0, stream>>>(
            (const int*)d_in[3], (const int*)d_in[4],
            (const int*)d_in[6], (const int*)d_in[7],
            (const int*)d_in[9], (const int*)d_in[10], deg2);
        scan3b_kernel<<<3, 256, 0, stream>>>(deg2, csrbase);
        fill3_kernel<<<ge, 256, 0, stream>>>(
            flag,
            (const int*)d_in[3], (const int*)d_in[4], d_in[5],
            (const int*)d_in[6], (const int*)d_in[7], d_in[8],
            (const int*)d_in[9], (const int*)d_in[10], d_in[11],
            deg2, cur2, csrbase);
    }

    // bf16-path pre-transposed weights (inside P_E slack)
    unsigned short* Wt1 = (unsigned short*)(ws + P_WT1);
    unsigned short* Wt2 = (unsigned short*)(ws + P_WT2);
    {
        dim3 g1(F_DIM / 64, H_DIM / 64, 9);
        transpose_w_kernel<<<g1, 256, 0, stream>>>(flag, d_in[12], Wt1, F_DIM, H_DIM);
        dim3 g2(H_DIM / 64, C_DIM / 64, 9);
        transpose_w_kernel<<<g2, 256, 0, stream>>>(flag, d_in[15], Wt2, H_DIM, C_DIM);
    }
    // fp32-path split W1 (in P_YSUM, dead until layer-2 combine; CSR scratch done)
    unsigned short* W1h = (unsigned short*)(ws + P_W1H);
    unsigned short* W1l = (unsigned short*)(ws + P_W1L);
    {
        dim3 g1(F_DIM / 64, H_DIM / 64, 9);
        split_w_kernel<<<g1, 256, 0, stream>>>(flag, (const float*)d_in[12],
                                               W1h, W1l, F_DIM, H_DIM);
    }

    // bf16-path table pointers (overlaid on P_E / P_H regions)
    unsigned short* Eb = (unsigned short*)(ws + P_E);
    unsigned short* Hb = (unsigned short*)(ws + P_H);

    const int gemmBlocks = (N_NODES + 63) / 64;         // 313

    // ---------------- layer 1: x -> h (H=128) ----------------
    for (int v = 0; v < 3; ++v) {
        int j0 = perm[v][0], j1 = perm[v][1], j2 = perm[v][2];
        dim3 g(gemmBlocks, 3);
        // bf16 path: batched MFMA
        gemm_mfma1_kernel<<<g, 256, 0, stream>>>(
            flag,
            (const unsigned short*)d_in[j0], (const unsigned short*)d_in[j1],
            (const unsigned short*)d_in[j2],
            Wt1 + (long)v * 3 * H_DIM * F_DIM, Eb, N_NODES);
        // fp32 path: batched split-bf16 MFMA
        gemm_mfma1f_kernel<<<g, 256, 0, stream>>>(
            flag,
            (const float*)d_in[j0], (const float*)d_in[j1], (const float*)d_in[j2],
            W1h + (long)v * 3 * H_DIM * F_DIM, W1l + (long)v * 3 * H_DIM * F_DIM,
            ws + P_E, N_NODES);

        spmm_bf16_kernel<128, false, true><<<N_NODES / 4, 256, 0, stream>>>(
            flag, rp[j0], ed[j0], rp[j1], ed[j1], rp[j2], ed[j2],
            Eb, Eb + (long)N_NODES * H_DIM, Eb + 2L * N_NODES * H_DIM,
            ws + P_WV1 + v * 3, ws + P_B1 + v * H_DIM,
            Hb + (long)v * N_NODES * H_DIM);
        spmm_f32_kernel<2, false><<<N_NODES / 4, 256, 0, stream>>>(
            flag, rp[j0], ed[j0], rp[j1], ed[j1], rp[j2], ed[j2],
            ws + P_E, ws + P_E + (long)N_NODES * H_DIM, ws + P_E + 2L * N_NODES * H_DIM,
            ws + P_WV1 + v * 3, ws + P_B1 + v * H_DIM,
            ws + P_H + (long)v * N_NODES * H_DIM);
    }

    // fp32-path split W2 (into dead L1-Er space; L2 Er uses only first 3.84M)
    unsigned short* W2h = (unsigned short*)(ws + P_W2H);
    unsigned short* W2l = (unsigned short*)(ws + P_W2L);
    {
        dim3 g2(H_DIM / 64, C_DIM / 64, 9);
        split_w_kernel<<<g2, 256, 0, stream>>>(flag, (const float*)d_in[15],
                                               W2h, W2l, H_DIM, C_DIM);
    }

    // ---------------- layer 2: h -> y (C=64), accumulate ysum ----------------
    for (int v = 0; v < 3; ++v) {
        int j0 = perm[v][0], j1 = perm[v][1], j2 = perm[v][2];
        dim3 g(gemmBlocks, 3);
        // bf16 path: batched MFMA
        gemm_mfma2_kernel<<<g, 256, 0, stream>>>(
            flag,
            Hb + (long)j0 * N_NODES * H_DIM, Hb + (long)j1 * N_NODES * H_DIM,
            Hb + (long)j2 * N_NODES * H_DIM,
            Wt2 + (long)v * 3 * C_DIM * H_DIM, Eb, N_NODES);
        // fp32 path: batched split-bf16 MFMA
        gemm_mfma2f_kernel<<<g, 256, 0, stream>>>(
            flag,
            ws + P_H + (long)j0 * N_NODES * H_DIM,
            ws + P_H + (long)j1 * N_NODES * H_DIM,
            ws + P_H + (long)j2 * N_NODES * H_DIM,
            W2h + (long)v * 3 * C_DIM * H_DIM, W2l + (long)v * 3 * C_DIM * H_DIM,
            ws + P_E, N_NODES);

        if (v == 0) {
            spmm_bf16_kernel<64, false, false><<<N_NODES / 8, 256, 0, stream>>>(
                flag, rp[j0], ed[j0], rp[j1], ed[j1], rp[j2], ed[j2],
                Eb, Eb + (long)N_NODES * C_DIM, Eb + 2L * N_NODES * C_DIM,
                ws + P_WV2 + v * 3, ws + P_B2 + v * C_DIM, ws + P_YSUM);
            spmm_f32_kernel<1, false><<<N_NODES / 4, 256, 0, stream>>>(
                flag, rp[j0], ed[j0], rp[j1], ed[j1], rp[j2], ed[j2],
                ws + P_E, ws + P_E + (long)N_NODES * C_DIM, ws + P_E + 2L * N_NODES * C_DIM,
                ws + P_WV2 + v * 3, ws + P_B2 + v * C_DIM, ws + P_YSUM);
        } else {
            spmm_bf16_kernel<64, true, false><<<N_NODES / 8, 256, 0, stream>>>(
                flag, rp[j0], ed[j0], rp[j1], ed[j1], rp[j2], ed[j2],
                Eb, Eb + (long)N_NODES * C_DIM, Eb + 2L * N_NODES * C_DIM,
                ws + P_WV2 + v * 3, ws + P_B2 + v * C_DIM, ws + P_YSUM);
            spmm_f32_kernel<1, true><<<N_NODES / 4, 256, 0, stream>>>(
                flag, rp[j0], ed[j0], rp[j1], ed[j1], rp[j2], ed[j2],
                ws + P_E, ws + P_E + (long)N_NODES * C_DIM, ws + P_E + 2L * N_NODES * C_DIM,
                ws + P_WV2 + v * 3, ws + P_B2 + v * C_DIM, ws + P_YSUM);
        }
    }

    final_kernel<__hip_bfloat16><<<(out_size + 255) / 256, 256, 0, stream>>>(
        flag, 0, ws + P_YSUM, (__hip_bfloat16*)d_out, out_size);
    final_kernel<float><<<(out_size + 255) / 256, 256, 0, stream>>>(
        flag, 1, ws + P_YSUM, (float*)d_out, out_size);
}

// Round 9
// 1082.560 us; speedup vs baseline: 1.1874x; 1.1874x over previous
//
#include <hip/hip_runtime.h>
#include <hip/hip_bf16.h>

// Problem constants (from the reference)
#define N_NODES 20000
#define F_DIM   512
#define H_DIM   128
#define C_DIM   64
#define E_EDGES 640000

// ---------------- workspace layout (float offsets from d_ws) ----------------
// flag: int at word 0 (1 = inputs are f32, 0 = inputs are bf16)
#define P_WV1   64                      // 9 floats
#define P_B1    80                      // 384 floats
#define P_WV2   464                     // 9
#define P_B2    480                     // 192 -> ends 672
#define P_E     1024                    // fp32 path: 3*N*H f32 | bf16 path: Er tables (bf16)
#define P_H     (P_E + 3*N_NODES*H_DIM) // fp32 path: 3*N*H f32 | bf16 path: h tables (bf16)
#define P_YSUM  (P_H + 3*N_NODES*H_DIM) // N*C f32 (both paths)
// CSR region: 3 adjacencies, each {rowptr[20032 ints], packed edges int2[E]}
// Edges within each row are written in dst-BUCKET order (bucket = dst>>12) so
// concurrently-running waves sweep dst-space together -> gather window stays
// L2-resident (r7 counters: 419MB L2-miss traffic vs ~45MB compulsory).
#define RP_SZ      20032
#define CSR_STRIDE (RP_SZ + 2*E_EDGES)          // in 4-byte words (unchanged)
#define P_CSR   (P_YSUM + N_NODES*C_DIM)
#define P_CUR   (P_CSR + 3*CSR_STRIDE)          // legacy scratch (unused now)
// bf16-path pre-transposed weights: inside P_E slack (bf16 Eb tables use
// <= 3.84M of the 7.68M words). Lifetimes flag-disjoint from fp32 path.
#define P_WT1   (P_E + 4000000)                 // 9*128*512 bf16 = 294912 words
#define P_WT2   (P_E + 4300000)                 // 9*64*128 bf16  = 36864 words
// fp32-path split weights (hi/lo bf16, k-major):
//  W1 pair in P_YSUM (free until layer-2 combine; 589824 <= 1.28M words)
//  W2 pair in P_E+4.0M, written BETWEEN layers (L1 Er dead, L2 Er <= 3.84M)
#define P_W1H   (P_YSUM)
#define P_W1L   (P_YSUM + 294912)
#define P_W2H   (P_E + 4000000)
#define P_W2L   (P_E + 4050000)
// CSR-build scratch: (src,bucket) histogram->scan (in place) + cursors + bsums.
// 2 x 3 x 160000 + 3 x 640 ints = ~962K words, in P_YSUM (1.28M words), dead
// during the build (W1 split + ysum writes come after, stream-ordered).
#define NBUCK       8                           // 5 used (dst>>12, dst<20000)
#define BUCK_SHIFT  12
#define B2_STRIDE   (N_NODES * NBUCK)           // 160000 = 625 * 256 exactly
#define NBLK_SCAN   625
#define BSUM_STRIDE 640
// total footprint unchanged at ~20.56M words = 82.2 MB (harness-verified)

typedef __attribute__((ext_vector_type(8))) unsigned short u16x8;
typedef __attribute__((ext_vector_type(8))) __bf16 bf16x8;
typedef __attribute__((ext_vector_type(4))) float f32x4;

__device__ inline float cvt(float x) { return x; }
__device__ inline float cvt(__hip_bfloat16 x) { return __bfloat162float(x); }

__device__ inline void store_out(float v, float* p) { *p = v; }
__device__ inline void store_out(float v, __hip_bfloat16* p) { *p = __float2bfloat16(v); }

__device__ inline unsigned short f2bf_bits(float x) {
    __hip_bfloat16 b = __float2bfloat16(x);
    return *(unsigned short*)&b;
}
// split fp32 -> (hi, lo) bf16 pair: x ~= hi + lo, |x-(hi+lo)| ~ 2^-17 |x|
__device__ inline void splitbf(float x, unsigned short& h, unsigned short& l) {
    h = f2bf_bits(x);
    float hf = __uint_as_float(((unsigned int)h) << 16);
    l = f2bf_bits(x - hf);
}

// ---------------- dtype probe ----------------
__global__ void detect_kernel(const unsigned short* __restrict__ x, int* flag) {
    __shared__ int cnt;
    if (threadIdx.x == 0) cnt = 0;
    __syncthreads();
    int c = 0;
    for (int i = threadIdx.x; i < 4096; i += 256) {
        int ex = (x[i] >> 7) & 0xff;
        if (ex >= 140) c++;
    }
    atomicAdd(&cnt, c);
    __syncthreads();
    if (threadIdx.x == 0) *flag = (cnt > 64) ? 1 : 0;
}

// Convert the small params (wv1,b1,wv2,b2) to fp32 in ws.
__global__ void prep_kernel(const int* __restrict__ flag,
                            const void* wv1, const void* b1,
                            const void* wv2, const void* b2, float* ws) {
    bool f32 = (*flag == 1);
    int t = threadIdx.x;
    auto get = [&](const void* p, int i) -> float {
        return f32 ? ((const float*)p)[i]
                   : __bfloat162float(((const __hip_bfloat16*)p)[i]);
    };
    if (t < 9) ws[P_WV1 + t] = get(wv1, t);
    if (t < 9) ws[P_WV2 + t] = get(wv2, t);
    for (int i = t; i < 3*H_DIM; i += 256) ws[P_B1 + i] = get(b1, i);
    for (int i = t; i < 3*C_DIM; i += 256) ws[P_B2 + i] = get(b2, i);
}

// ---------------- CSR build (batched, dst-bucket-ordered rows) --------------
// histogram over (src, dst-bucket)
__global__ __launch_bounds__(256)
void hist2_kernel(const int* __restrict__ s0, const int* __restrict__ d0,
                  const int* __restrict__ s1, const int* __restrict__ d1,
                  const int* __restrict__ s2, const int* __restrict__ d2,
                  int* __restrict__ deg2) {
    int e = blockIdx.x * 256 + threadIdx.x;
    if (e >= E_EDGES) return;
    const int z = blockIdx.y;
    const int* src = (z == 0) ? s0 : (z == 1) ? s1 : s2;
    const int* dst = (z == 0) ? d0 : (z == 1) ? d1 : d2;
    int idx = src[e] * NBUCK + (dst[e] >> BUCK_SHIFT);
    atomicAdd(&deg2[z * B2_STRIDE + idx], 1);
}

// Parallel 3-phase exclusive scan over deg2 (r8 post-mortem: the single-block
// serial scan was 218us at 3 CUs busy; this is ~20us total).
// Phase A: per-256-entry block local exclusive scan + block sums.
__global__ __launch_bounds__(256)
void scanA_kernel(int* __restrict__ deg2, int* __restrict__ bsum) {
    __shared__ int s[256];
    const int z = blockIdx.y;
    int* d = deg2 + z * B2_STRIDE;
    const int t = threadIdx.x;
    const int i = blockIdx.x * 256 + t;         // 625*256 = 160000 exact
    int v = d[i];
    s[t] = v;
    __syncthreads();
    for (int off = 1; off < 256; off <<= 1) {
        int u = (t >= off) ? s[t - off] : 0;
        __syncthreads();
        s[t] += u;
        __syncthreads();
    }
    d[i] = s[t] - v;                            // local exclusive
    if (t == 255) bsum[z * BSUM_STRIDE + blockIdx.x] = s[255];
}

// Phase B: exclusive scan of the 625 block sums per adjacency (3 blocks).
__global__ __launch_bounds__(256)
void scanB_kernel(int* __restrict__ bsum) {
    __shared__ int sums[256];
    int* b = bsum + blockIdx.x * BSUM_STRIDE;
    const int t = threadIdx.x;
    int beg = t * 3, end = beg + 3; if (end > NBLK_SCAN) end = NBLK_SCAN;
    int s = 0;
    for (int i = beg; i < end && i < NBLK_SCAN; ++i) s += b[i];
    sums[t] = s;
    __syncthreads();
    for (int off = 1; off < 256; off <<= 1) {
        int u = (t >= off) ? sums[t - off] : 0;
        __syncthreads();
        sums[t] += u;
        __syncthreads();
    }
    int run = sums[t] - s;
    for (int i = beg; i < end && i < NBLK_SCAN; ++i) { int v = b[i]; b[i] = run; run += v; }
}

// Phase C: add block offsets; emit per-node rowptr (+ total = E_EDGES).
__global__ __launch_bounds__(256)
void scanC_kernel(int* __restrict__ deg2, const int* __restrict__ bsum,
                  int* __restrict__ rpBase) {
    const int z = blockIdx.y;
    int* d = deg2 + z * B2_STRIDE;
    int* rowptr = rpBase + (long)z * CSR_STRIDE;
    const int i = blockIdx.x * 256 + threadIdx.x;
    int v = d[i] + bsum[z * BSUM_STRIDE + blockIdx.x];
    d[i] = v;
    if ((i & (NBUCK - 1)) == 0) rowptr[i >> 3] = v;
    if (i == 0) rowptr[N_NODES] = E_EDGES;
}

// one launch fills all 3 CSRs; val dtype chosen by flag at runtime.
// Position = (src,bucket) start + cursor -> rows end up dst-bucket-sorted.
__global__ __launch_bounds__(256)
void fill3_kernel(const int* __restrict__ flag,
                  const int* __restrict__ s0, const int* __restrict__ d0,
                  const void* __restrict__ v0,
                  const int* __restrict__ s1, const int* __restrict__ d1,
                  const void* __restrict__ v1,
                  const int* __restrict__ s2, const int* __restrict__ d2,
                  const void* __restrict__ v2,
                  const int* __restrict__ deg2, int* __restrict__ cur2,
                  int* __restrict__ rpBase) {
    int e = blockIdx.x * 256 + threadIdx.x;
    if (e >= E_EDGES) return;
    const int z = blockIdx.y;
    const int* src = (z == 0) ? s0 : (z == 1) ? s1 : s2;
    const int* dst = (z == 0) ? d0 : (z == 1) ? d1 : d2;
    const void* val = (z == 0) ? v0 : (z == 1) ? v1 : v2;
    float v = (*flag == 1) ? ((const float*)val)[e]
                           : __bfloat162float(((const __hip_bfloat16*)val)[e]);
    int d = dst[e];
    int idx = z * B2_STRIDE + src[e] * NBUCK + (d >> BUCK_SHIFT);
    int pos = deg2[idx] + atomicAdd(&cur2[idx], 1);
    int2* ed = (int2*)(rpBase + (long)z * CSR_STRIDE + RP_SZ);
    ed[pos] = make_int2(d, __float_as_int(v));
}

// ---------------- weight transpose (bf16 path) ----------------
// W [z][K][HO] bf16  ->  Wt [z][HO][K] bf16
__global__ __launch_bounds__(256)
void transpose_w_kernel(const int* __restrict__ flag,
                        const void* __restrict__ Wsrc,
                        unsigned short* __restrict__ Wt, int K, int HO) {
    if (*flag != 0) return;
    __shared__ unsigned short T[64][80];        // pad 80: 16B-aligned vec rows
    const unsigned short* W = (const unsigned short*)Wsrc + (long)blockIdx.z * K * HO;
    unsigned short* O = Wt + (long)blockIdx.z * HO * K;
    const int k0 = blockIdx.x * 64, n0 = blockIdx.y * 64;
    const int t = threadIdx.x;
    const int rr = t >> 3, cc = (t & 7) * 8;
    #pragma unroll
    for (int i = 0; i < 2; ++i) {
        int k = rr + i * 32;
        *(u16x8*)&T[k][cc] = *(const u16x8*)&W[(long)(k0 + k) * HO + n0 + cc];
    }
    __syncthreads();
    #pragma unroll
    for (int i = 0; i < 2; ++i) {
        int nn = rr + i * 32;
        u16x8 v;
        #pragma unroll
        for (int j = 0; j < 8; ++j) v[j] = T[cc + j][nn];
        *(u16x8*)&O[(long)(n0 + nn) * K + k0 + cc] = v;
    }
}

// ---------------- weight transpose + hi/lo split (fp32 path) ----------------
// W [z][K][HO] f32 -> Wh/Wl [z][HO][K] bf16
__global__ __launch_bounds__(256)
void split_w_kernel(const int* __restrict__ flag,
                    const float* __restrict__ Wsrc,
                    unsigned short* __restrict__ Wh,
                    unsigned short* __restrict__ Wl, int K, int HO) {
    if (*flag != 1) return;
    __shared__ float T[64][68];
    const float* W = Wsrc + (long)blockIdx.z * K * HO;
    unsigned short* Oh = Wh + (long)blockIdx.z * HO * K;
    unsigned short* Ol = Wl + (long)blockIdx.z * HO * K;
    const int k0 = blockIdx.x * 64, n0 = blockIdx.y * 64;
    const int t = threadIdx.x;
    #pragma unroll
    for (int i = 0; i < 16; ++i) {
        int idx = t + i * 256;
        int r = idx >> 6, c = idx & 63;
        T[r][c] = W[(long)(k0 + r) * HO + n0 + c];
    }
    __syncthreads();
    #pragma unroll
    for (int i = 0; i < 16; ++i) {
        int idx = t + i * 256;
        int nn = idx >> 6, kk = idx & 63;
        unsigned short h, l;
        splitbf(T[kk][nn], h, l);
        Oh[(long)(n0 + nn) * K + k0 + kk] = h;
        Ol[(long)(n0 + nn) * K + k0 + kk] = l;
    }
}

// ---------------- MFMA GEMM layer 1 (bf16): out[N,128]bf16 = X[N,512] @ W ----
#define SWZ(r, kb) (((r) << 7) + ((kb) ^ (((r) & 7) << 4)))

__global__ __launch_bounds__(256)
void gemm_mfma1_kernel(const int* __restrict__ flag,
                       const unsigned short* __restrict__ x0,
                       const unsigned short* __restrict__ x1,
                       const unsigned short* __restrict__ x2,
                       const unsigned short* __restrict__ WtBase,
                       unsigned short* __restrict__ outBase, int n) {
    if (*flag != 0) return;
    const int role = blockIdx.y;
    const unsigned short* X = (role == 0) ? x0 : (role == 1) ? x1 : x2;
    const unsigned short* Wt = WtBase + (long)role * H_DIM * F_DIM;
    unsigned short* out = outBase + (long)role * N_NODES * H_DIM;
    __shared__ __align__(16) unsigned short As[64 * 64];
    __shared__ __align__(16) unsigned short Bs[128 * 64];
    const int t = threadIdx.x;
    const int lane = t & 63;
    const int wave = t >> 6;
    const int wm = wave & 1, wn = wave >> 1;
    const int row0 = blockIdx.x * 64;
    const int rl = lane & 15;
    const int kq = lane >> 4;                   // 0..3
    const int sr = t >> 3;                      // staging row (0..31)
    const int sc = (t & 7) * 8;                 // staging k offset (elements)
    f32x4 acc[2][4] = {};
    for (int k0 = 0; k0 < F_DIM; k0 += 64) {
        #pragma unroll
        for (int i = 0; i < 2; ++i) {           // A: 64 rows x 64 k
            int r = i * 32 + sr;
            int gr = row0 + r; if (gr >= n) gr = n - 1;   // clamp, store-guarded
            u16x8 v = *(const u16x8*)&X[(long)gr * F_DIM + k0 + sc];
            *(u16x8*)((char*)As + SWZ(r, sc * 2)) = v;
        }
        #pragma unroll
        for (int i = 0; i < 4; ++i) {           // B: 128 n-rows x 64 k
            int r = i * 32 + sr;
            u16x8 v = *(const u16x8*)&Wt[(long)r * F_DIM + k0 + sc];
            *(u16x8*)((char*)Bs + SWZ(r, sc * 2)) = v;
        }
        __syncthreads();
        #pragma unroll
        for (int s = 0; s < 2; ++s) {           // two K=32 sub-steps
            const int kb = s * 64 + kq * 16;    // lane's 16B within the row
            bf16x8 af[2], bfr[4];
            #pragma unroll
            for (int mi = 0; mi < 2; ++mi) {
                int r = wm * 32 + mi * 16 + rl;
                af[mi] = *(const bf16x8*)((const char*)As + SWZ(r, kb));
            }
            #pragma unroll
            for (int ni = 0; ni < 4; ++ni) {
                int r = wn * 64 + ni * 16 + rl;
                bfr[ni] = *(const bf16x8*)((const char*)Bs + SWZ(r, kb));
            }
            #pragma unroll
            for (int mi = 0; mi < 2; ++mi)
                #pragma unroll
                for (int ni = 0; ni < 4; ++ni)
                    acc[mi][ni] = __builtin_amdgcn_mfma_f32_16x16x32_bf16(
                        af[mi], bfr[ni], acc[mi][ni], 0, 0, 0);
        }
        __syncthreads();
    }
    #pragma unroll
    for (int mi = 0; mi < 2; ++mi) {
        #pragma unroll
        for (int q = 0; q < 4; ++q) {
            int row = row0 + wm * 32 + mi * 16 + kq * 4 + q;
            if (row < n) {
                #pragma unroll
                for (int ni = 0; ni < 4; ++ni) {
                    int col = wn * 64 + ni * 16 + rl;
                    out[(long)row * H_DIM + col] = f2bf_bits(acc[mi][ni][q]);
                }
            }
        }
    }
}

// ---------------- MFMA GEMM layer 1 (fp32 path, split-bf16 3-product) -------
__global__ __launch_bounds__(256)
void gemm_mfma1f_kernel(const int* __restrict__ flag,
                        const float* __restrict__ x0,
                        const float* __restrict__ x1,
                        const float* __restrict__ x2,
                        const unsigned short* __restrict__ WhBase,
                        const unsigned short* __restrict__ WlBase,
                        float* __restrict__ outBase, int n) {
    if (*flag != 1) return;
    const int role = blockIdx.y;
    const float* X = (role == 0) ? x0 : (role == 1) ? x1 : x2;
    const unsigned short* Wh = WhBase + (long)role * H_DIM * F_DIM;
    const unsigned short* Wl = WlBase + (long)role * H_DIM * F_DIM;
    float* out = outBase + (long)role * N_NODES * H_DIM;
    __shared__ __align__(16) unsigned short Ash[64 * 64];
    __shared__ __align__(16) unsigned short Asl[64 * 64];
    __shared__ __align__(16) unsigned short Bsh[128 * 64];
    __shared__ __align__(16) unsigned short Bsl[128 * 64];
    const int t = threadIdx.x;
    const int lane = t & 63;
    const int wave = t >> 6;
    const int wm = wave & 1, wn = wave >> 1;
    const int row0 = blockIdx.x * 64;
    const int rl = lane & 15;
    const int kq = lane >> 4;
    const int sr = t >> 3;
    const int sc = (t & 7) * 8;
    f32x4 acc[2][4] = {};
    for (int k0 = 0; k0 < F_DIM; k0 += 64) {
        #pragma unroll
        for (int i = 0; i < 2; ++i) {           // A: 64 rows x 64 k, split on the fly
            int r = i * 32 + sr;
            int gr = row0 + r; if (gr >= n) gr = n - 1;
            float4 v0 = *(const float4*)&X[(long)gr * F_DIM + k0 + sc];
            float4 v1 = *(const float4*)&X[(long)gr * F_DIM + k0 + sc + 4];
            float xs[8] = {v0.x, v0.y, v0.z, v0.w, v1.x, v1.y, v1.z, v1.w};
            u16x8 hi, lo;
            #pragma unroll
            for (int j = 0; j < 8; ++j) { unsigned short h, l; splitbf(xs[j], h, l); hi[j] = h; lo[j] = l; }
            *(u16x8*)((char*)Ash + SWZ(r, sc * 2)) = hi;
            *(u16x8*)((char*)Asl + SWZ(r, sc * 2)) = lo;
        }
        #pragma unroll
        for (int i = 0; i < 4; ++i) {           // B: 128 n-rows x 64 k (pre-split)
            int r = i * 32 + sr;
            u16x8 vh = *(const u16x8*)&Wh[(long)r * F_DIM + k0 + sc];
            u16x8 vl = *(const u16x8*)&Wl[(long)r * F_DIM + k0 + sc];
            *(u16x8*)((char*)Bsh + SWZ(r, sc * 2)) = vh;
            *(u16x8*)((char*)Bsl + SWZ(r, sc * 2)) = vl;
        }
        __syncthreads();
        #pragma unroll
        for (int s = 0; s < 2; ++s) {
            const int kb = s * 64 + kq * 16;
            bf16x8 ah[2], al[2], bh[4], bl[4];
            #pragma unroll
            for (int mi = 0; mi < 2; ++mi) {
                int r = wm * 32 + mi * 16 + rl;
                ah[mi] = *(const bf16x8*)((const char*)Ash + SWZ(r, kb));
                al[mi] = *(const bf16x8*)((const char*)Asl + SWZ(r, kb));
            }
            #pragma unroll
            for (int ni = 0; ni < 4; ++ni) {
                int r = wn * 64 + ni * 16 + rl;
                bh[ni] = *(const bf16x8*)((const char*)Bsh + SWZ(r, kb));
                bl[ni] = *(const bf16x8*)((const char*)Bsl + SWZ(r, kb));
            }
            #pragma unroll
            for (int mi = 0; mi < 2; ++mi)
                #pragma unroll
                for (int ni = 0; ni < 4; ++ni) {
                    acc[mi][ni] = __builtin_amdgcn_mfma_f32_16x16x32_bf16(
                        ah[mi], bh[ni], acc[mi][ni], 0, 0, 0);
                    acc[mi][ni] = __builtin_amdgcn_mfma_f32_16x16x32_bf16(
                        ah[mi], bl[ni], acc[mi][ni], 0, 0, 0);
                    acc[mi][ni] = __builtin_amdgcn_mfma_f32_16x16x32_bf16(
                        al[mi], bh[ni], acc[mi][ni], 0, 0, 0);
                }
        }
        __syncthreads();
    }
    #pragma unroll
    for (int mi = 0; mi < 2; ++mi) {
        #pragma unroll
        for (int q = 0; q < 4; ++q) {
            int row = row0 + wm * 32 + mi * 16 + kq * 4 + q;
            if (row < n) {
                #pragma unroll
                for (int ni = 0; ni < 4; ++ni) {
                    int col = wn * 64 + ni * 16 + rl;
                    out[(long)row * H_DIM + col] = acc[mi][ni][q];
                }
            }
        }
    }
}

// ---------------- MFMA GEMM layer 2 (bf16): out[N,64]bf16 = h[N,128] @ W2 ----
#define SWZ2(r, kb) (((r) << 8) + ((kb) ^ (((r) & 7) << 4)))

__global__ __launch_bounds__(256)
void gemm_mfma2_kernel(const int* __restrict__ flag,
                       const unsigned short* __restrict__ h0,
                       const unsigned short* __restrict__ h1,
                       const unsigned short* __restrict__ h2,
                       const unsigned short* __restrict__ WtBase,
                       unsigned short* __restrict__ outBase, int n) {
    if (*flag != 0) return;
    const int role = blockIdx.y;
    const unsigned short* X = (role == 0) ? h0 : (role == 1) ? h1 : h2;
    const unsigned short* Wt = WtBase + (long)role * C_DIM * H_DIM;
    unsigned short* out = outBase + (long)role * N_NODES * C_DIM;
    __shared__ __align__(16) unsigned short As[64 * 128];
    __shared__ __align__(16) unsigned short Bs[64 * 128];
    const int t = threadIdx.x;
    const int lane = t & 63;
    const int wave = t >> 6;
    const int wm = wave & 1, wn = wave >> 1;
    const int row0 = blockIdx.x * 64;
    const int rl = lane & 15;
    const int kq = lane >> 4;
    #pragma unroll
    for (int i = 0; i < 4; ++i) {
        int e = t + i * 256;
        int r = e >> 4, c8 = e & 15;
        int gr = row0 + r; if (gr >= n) gr = n - 1;
        u16x8 va = *(const u16x8*)&X[(long)gr * H_DIM + c8 * 8];
        *(u16x8*)((char*)As + SWZ2(r, c8 * 16)) = va;
        u16x8 vb = *(const u16x8*)&Wt[(long)r * H_DIM + c8 * 8];
        *(u16x8*)((char*)Bs + SWZ2(r, c8 * 16)) = vb;
    }
    __syncthreads();
    f32x4 acc[2][2] = {};
    #pragma unroll
    for (int s = 0; s < 4; ++s) {
        const int kb = s * 64 + kq * 16;
        bf16x8 af[2], bfr[2];
        #pragma unroll
        for (int mi = 0; mi < 2; ++mi) {
            int r = wm * 32 + mi * 16 + rl;
            af[mi] = *(const bf16x8*)((const char*)As + SWZ2(r, kb));
        }
        #pragma unroll
        for (int ni = 0; ni < 2; ++ni) {
            int r = wn * 32 + ni * 16 + rl;
            bfr[ni] = *(const bf16x8*)((const char*)Bs + SWZ2(r, kb));
        }
        #pragma unroll
        for (int mi = 0; mi < 2; ++mi)
            #pragma unroll
            for (int ni = 0; ni < 2; ++ni)
                acc[mi][ni] = __builtin_amdgcn_mfma_f32_16x16x32_bf16(
                    af[mi], bfr[ni], acc[mi][ni], 0, 0, 0);
    }
    #pragma unroll
    for (int mi = 0; mi < 2; ++mi) {
        #pragma unroll
        for (int q = 0; q < 4; ++q) {
            int row = row0 + wm * 32 + mi * 16 + kq * 4 + q;
            if (row < n) {
                #pragma unroll
                for (int ni = 0; ni < 2; ++ni) {
                    int col = wn * 32 + ni * 16 + rl;
                    out[(long)row * C_DIM + col] = f2bf_bits(acc[mi][ni][q]);
                }
            }
        }
    }
}

// ---------------- MFMA GEMM layer 2 (fp32 path, split-bf16 3-product) -------
__global__ __launch_bounds__(256)
void gemm_mfma2f_kernel(const int* __restrict__ flag,
                        const float* __restrict__ h0,
                        const float* __restrict__ h1,
                        const float* __restrict__ h2,
                        const unsigned short* __restrict__ WhBase,
                        const unsigned short* __restrict__ WlBase,
                        float* __restrict__ outBase, int n) {
    if (*flag != 1) return;
    const int role = blockIdx.y;
    const float* X = (role == 0) ? h0 : (role == 1) ? h1 : h2;
    const unsigned short* Wh = WhBase + (long)role * C_DIM * H_DIM;
    const unsigned short* Wl = WlBase + (long)role * C_DIM * H_DIM;
    float* out = outBase + (long)role * N_NODES * C_DIM;
    __shared__ __align__(16) unsigned short Ash[64 * 128];
    __shared__ __align__(16) unsigned short Asl[64 * 128];
    __shared__ __align__(16) unsigned short Bsh[64 * 128];
    __shared__ __align__(16) unsigned short Bsl[64 * 128];
    const int t = threadIdx.x;
    const int lane = t & 63;
    const int wave = t >> 6;
    const int wm = wave & 1, wn = wave >> 1;
    const int row0 = blockIdx.x * 64;
    const int rl = lane & 15;
    const int kq = lane >> 4;
    #pragma unroll
    for (int i = 0; i < 4; ++i) {
        int e = t + i * 256;
        int r = e >> 4, c8 = e & 15;
        int gr = row0 + r; if (gr >= n) gr = n - 1;
        float4 v0 = *(const float4*)&X[(long)gr * H_DIM + c8 * 8];
        float4 v1 = *(const float4*)&X[(long)gr * H_DIM + c8 * 8 + 4];
        float xs[8] = {v0.x, v0.y, v0.z, v0.w, v1.x, v1.y, v1.z, v1.w};
        u16x8 hi, lo;
        #pragma unroll
        for (int j = 0; j < 8; ++j) { unsigned short h, l; splitbf(xs[j], h, l); hi[j] = h; lo[j] = l; }
        *(u16x8*)((char*)Ash + SWZ2(r, c8 * 16)) = hi;
        *(u16x8*)((char*)Asl + SWZ2(r, c8 * 16)) = lo;
        u16x8 vh = *(const u16x8*)&Wh[(long)r * H_DIM + c8 * 8];
        u16x8 vl = *(const u16x8*)&Wl[(long)r * H_DIM + c8 * 8];
        *(u16x8*)((char*)Bsh + SWZ2(r, c8 * 16)) = vh;
        *(u16x8*)((char*)Bsl + SWZ2(r, c8 * 16)) = vl;
    }
    __syncthreads();
    f32x4 acc[2][2] = {};
    #pragma unroll
    for (int s = 0; s < 4; ++s) {
        const int kb = s * 64 + kq * 16;
        bf16x8 ah[2], al[2], bh[2], bl[2];
        #pragma unroll
        for (int mi = 0; mi < 2; ++mi) {
            int r = wm * 32 + mi * 16 + rl;
            ah[mi] = *(const bf16x8*)((const char*)Ash + SWZ2(r, kb));
            al[mi] = *(const bf16x8*)((const char*)Asl + SWZ2(r, kb));
        }
        #pragma unroll
        for (int ni = 0; ni < 2; ++ni) {
            int r = wn * 32 + ni * 16 + rl;
            bh[ni] = *(const bf16x8*)((const char*)Bsh + SWZ2(r, kb));
            bl[ni] = *(const bf16x8*)((const char*)Bsl + SWZ2(r, kb));
        }
        #pragma unroll
        for (int mi = 0; mi < 2; ++mi)
            #pragma unroll
            for (int ni = 0; ni < 2; ++ni) {
                acc[mi][ni] = __builtin_amdgcn_mfma_f32_16x16x32_bf16(
                    ah[mi], bh[ni], acc[mi][ni], 0, 0, 0);
                acc[mi][ni] = __builtin_amdgcn_mfma_f32_16x16x32_bf16(
                    ah[mi], bl[ni], acc[mi][ni], 0, 0, 0);
                acc[mi][ni] = __builtin_amdgcn_mfma_f32_16x16x32_bf16(
                    al[mi], bh[ni], acc[mi][ni], 0, 0, 0);
            }
    }
    #pragma unroll
    for (int mi = 0; mi < 2; ++mi) {
        #pragma unroll
        for (int q = 0; q < 4; ++q) {
            int row = row0 + wm * 32 + mi * 16 + kq * 4 + q;
            if (row < n) {
                #pragma unroll
                for (int ni = 0; ni < 2; ++ni) {
                    int col = wn * 32 + ni * 16 + rl;
                    out[(long)row * C_DIM + col] = acc[mi][ni][q];
                }
            }
        }
    }
}

// ---------------- fused CSR SpMM, fp32 tables (fp32 path), packed edges -----
template <int FP, bool ACCUM>
__global__ __launch_bounds__(256)
void spmm_f32_kernel(const int* __restrict__ flag,
                     const int* __restrict__ rp0, const int2* __restrict__ ed0,
                     const int* __restrict__ rp1, const int2* __restrict__ ed1,
                     const int* __restrict__ rp2, const int2* __restrict__ ed2,
                     const float* __restrict__ Et0, const float* __restrict__ Et1,
                     const float* __restrict__ Et2,
                     const float* __restrict__ wvp, const float* __restrict__ bias,
                     float* __restrict__ out) {
    if (*flag != 1) return;
    constexpr int HO = FP * 64;
    const int node = blockIdx.x * 4 + (threadIdx.x >> 6);
    const int lane = threadIdx.x & 63;
    const int fbase = lane * FP;
    float acc[FP];
    #pragma unroll
    for (int k = 0; k < FP; ++k) acc[k] = 0.f;

    const int*  rps[3] = {rp0, rp1, rp2};
    const int2* eds[3] = {ed0, ed1, ed2};
    const float* Ets[3] = {Et0, Et1, Et2};
    #pragma unroll
    for (int r = 0; r < 3; ++r) {
        const float s = 1.01f * wvp[r];
        const int2* ed = eds[r];
        const float* Et = Ets[r] + fbase;
        int e = rps[r][node];
        const int end = rps[r][node + 1];
        // 8 independent gathers in flight
        for (; e + 8 <= end; e += 8) {
            int2 E[8]; float vv[8]; const float* rr[8];
            #pragma unroll
            for (int q = 0; q < 8; ++q) E[q] = ed[e + q];
            #pragma unroll
            for (int q = 0; q < 8; ++q) {
                vv[q] = s * __int_as_float(E[q].y);
                rr[q] = Et + (long)E[q].x * HO;
            }
            #pragma unroll
            for (int q = 0; q < 8; ++q)
                #pragma unroll
                for (int k = 0; k < FP; ++k) acc[k] += vv[q] * rr[q][k];
        }
        for (; e + 2 <= end; e += 2) {
            int2 E0 = ed[e], E1 = ed[e + 1];
            float v0 = s * __int_as_float(E0.y), v1 = s * __int_as_float(E1.y);
            const float* r0 = Et + (long)E0.x * HO;
            const float* r1 = Et + (long)E1.x * HO;
            #pragma unroll
            for (int k = 0; k < FP; ++k) acc[k] += v0 * r0[k];
            #pragma unroll
            for (int k = 0; k < FP; ++k) acc[k] += v1 * r1[k];
        }
        if (e < end) {
            int2 E0 = ed[e];
            float v0 = s * __int_as_float(E0.y);
            const float* r0 = Et + (long)E0.x * HO;
            #pragma unroll
            for (int k = 0; k < FP; ++k) acc[k] += v0 * r0[k];
        }
    }
    const float* e0 = Et0 + (long)node * HO + fbase;
    const float* bp = bias + fbase;
    float* o = out + (long)node * HO + fbase;
    #pragma unroll
    for (int k = 0; k < FP; ++k) {
        float x = e0[k] + acc[k] + bp[k];
        x = x > 0.f ? x : 0.f;
        if (ACCUM) o[k] += x; else o[k] = x;
    }
}

// ---------------- fused CSR SpMM, bf16 tables (bf16 path), packed edges -----
template <int HO, bool ACCUM, bool OUT_BF16>
__global__ __launch_bounds__(256)
void spmm_bf16_kernel(const int* __restrict__ flag,
                      const int* __restrict__ rp0, const int2* __restrict__ ed0,
                      const int* __restrict__ rp1, const int2* __restrict__ ed1,
                      const int* __restrict__ rp2, const int2* __restrict__ ed2,
                      const unsigned short* __restrict__ Et0,
                      const unsigned short* __restrict__ Et1,
                      const unsigned short* __restrict__ Et2,
                      const float* __restrict__ wvp, const float* __restrict__ bias,
                      void* __restrict__ outp) {
    if (*flag != 0) return;
    constexpr int NL = HO / 2;                  // lanes per node
    constexpr int NPW = 64 / NL;                // nodes per wave
    const int t = threadIdx.x;
    const int lane = t & 63;
    const int li = lane % NL;
    const int node = blockIdx.x * (4 * NPW) + (t >> 6) * NPW + lane / NL;
    const int fl = li * 2;
    float a0 = 0.f, a1 = 0.f;

    const int*  rps[3] = {rp0, rp1, rp2};
    const int2* eds[3] = {ed0, ed1, ed2};
    const unsigned int* Ets[3] = {(const unsigned int*)Et0,
                                  (const unsigned int*)Et1,
                                  (const unsigned int*)Et2};
    #pragma unroll
    for (int r = 0; r < 3; ++r) {
        const float s = 1.01f * wvp[r];
        const int2* ed = eds[r];
        const unsigned int* Et = Ets[r] + li;   // word index: d*NL + li
        int e = rps[r][node];
        const int end = rps[r][node + 1];
        for (; e + 4 <= end; e += 4) {
            int2 E0 = ed[e], E1 = ed[e + 1], E2 = ed[e + 2], E3 = ed[e + 3];
            float v0 = s * __int_as_float(E0.y), v1 = s * __int_as_float(E1.y);
            float v2 = s * __int_as_float(E2.y), v3 = s * __int_as_float(E3.y);
            unsigned int w0 = Et[(long)E0.x * NL];
            unsigned int w1 = Et[(long)E1.x * NL];
            unsigned int w2 = Et[(long)E2.x * NL];
            unsigned int w3 = Et[(long)E3.x * NL];
            a0 += v0 * __uint_as_float(w0 << 16);
            a1 += v0 * __uint_as_float(w0 & 0xffff0000u);
            a0 += v1 * __uint_as_float(w1 << 16);
            a1 += v1 * __uint_as_float(w1 & 0xffff0000u);
            a0 += v2 * __uint_as_float(w2 << 16);
            a1 += v2 * __uint_as_float(w2 & 0xffff0000u);
            a0 += v3 * __uint_as_float(w3 << 16);
            a1 += v3 * __uint_as_float(w3 & 0xffff0000u);
        }
        for (; e < end; ++e) {
            int2 E0 = ed[e];
            float v0 = s * __int_as_float(E0.y);
            unsigned int w0 = Et[(long)E0.x * NL];
            a0 += v0 * __uint_as_float(w0 << 16);
            a1 += v0 * __uint_as_float(w0 & 0xffff0000u);
        }
    }
    unsigned int ws0 = ((const unsigned int*)Et0)[(long)node * NL + li];
    float x0 = __uint_as_float(ws0 << 16)        + a0 + bias[fl];
    float x1 = __uint_as_float(ws0 & 0xffff0000u) + a1 + bias[fl + 1];
    x0 = x0 > 0.f ? x0 : 0.f;
    x1 = x1 > 0.f ? x1 : 0.f;
    if (OUT_BF16) {
        unsigned int packed = ((unsigned int)f2bf_bits(x1) << 16) | f2bf_bits(x0);
        ((unsigned int*)outp)[(long)node * NL + li] = packed;
    } else {
        float* o = (float*)outp + (long)node * HO + fl;
        if (ACCUM) { o[0] += x0; o[1] += x1; }
        else       { o[0] = x0;  o[1] = x1; }
    }
}

template <typename TOUT>
__global__ __launch_bounds__(256)
void final_kernel(const int* __restrict__ flag, int want,
                  const float* __restrict__ ysum, TOUT* __restrict__ out, int n) {
    if (*flag != want) return;
    int i = blockIdx.x * 256 + threadIdx.x;
    if (i >= n) return;
    store_out(fabsf(ysum[i] * (1.f / 3.f)), &out[i]);
}

extern "C" void kernel_launch(void* const* d_in, const int* in_sizes, int n_in,
                              void* d_out, int out_size, void* d_ws, size_t ws_size,
                              hipStream_t stream) {
    float* ws = (float*)d_ws;
    int* flag = (int*)d_ws;
    static const int perm[3][3] = {{0, 1, 2}, {1, 0, 2}, {2, 0, 1}};

    detect_kernel<<<1, 256, 0, stream>>>((const unsigned short*)d_in[0], flag);
    prep_kernel<<<1, 256, 0, stream>>>(flag, d_in[13], d_in[14], d_in[16], d_in[17], ws);

    // ---------------- CSR build (bucket-ordered; scratch in dead P_YSUM) ----
    int* csrbase = (int*)(ws + P_CSR);
    int* rp[3]; int2* ed[3];
    for (int j = 0; j < 3; ++j) {
        rp[j] = csrbase + (long)j * CSR_STRIDE;
        ed[j] = (int2*)(rp[j] + RP_SZ);
    }
    {
        int* deg2 = (int*)(ws + P_YSUM);                // 3 x 160000
        int* cur2 = deg2 + 3 * B2_STRIDE;               // 3 x 160000
        int* bsum = cur2 + 3 * B2_STRIDE;               // 3 x 640
        hipMemsetAsync(deg2, 0, (size_t)6 * B2_STRIDE * 4, stream);
        dim3 ge((E_EDGES + 255) / 256, 3);
        hist2_kernel<<<ge, 256, 0, stream>>>(
            (const int*)d_in[3], (const int*)d_in[4],
            (const int*)d_in[6], (const int*)d_in[7],
            (const int*)d_in[9], (const int*)d_in[10], deg2);
        dim3 gs(NBLK_SCAN, 3);
        scanA_kernel<<<gs, 256, 0, stream>>>(deg2, bsum);
        scanB_kernel<<<3, 256, 0, stream>>>(bsum);
        scanC_kernel<<<gs, 256, 0, stream>>>(deg2, bsum, csrbase);
        fill3_kernel<<<ge, 256, 0, stream>>>(
            flag,
            (const int*)d_in[3], (const int*)d_in[4], d_in[5],
            (const int*)d_in[6], (const int*)d_in[7], d_in[8],
            (const int*)d_in[9], (const int*)d_in[10], d_in[11],
            deg2, cur2, csrbase);
    }

    // bf16-path pre-transposed weights (inside P_E slack)
    unsigned short* Wt1 = (unsigned short*)(ws + P_WT1);
    unsigned short* Wt2 = (unsigned short*)(ws + P_WT2);
    {
        dim3 g1(F_DIM / 64, H_DIM / 64, 9);
        transpose_w_kernel<<<g1, 256, 0, stream>>>(flag, d_in[12], Wt1, F_DIM, H_DIM);
        dim3 g2(H_DIM / 64, C_DIM / 64, 9);
        transpose_w_kernel<<<g2, 256, 0, stream>>>(flag, d_in[15], Wt2, H_DIM, C_DIM);
    }
    // fp32-path split W1 (in P_YSUM, dead until layer-2 combine; CSR scratch done)
    unsigned short* W1h = (unsigned short*)(ws + P_W1H);
    unsigned short* W1l = (unsigned short*)(ws + P_W1L);
    {
        dim3 g1(F_DIM / 64, H_DIM / 64, 9);
        split_w_kernel<<<g1, 256, 0, stream>>>(flag, (const float*)d_in[12],
                                               W1h, W1l, F_DIM, H_DIM);
    }

    // bf16-path table pointers (overlaid on P_E / P_H regions)
    unsigned short* Eb = (unsigned short*)(ws + P_E);
    unsigned short* Hb = (unsigned short*)(ws + P_H);

    const int gemmBlocks = (N_NODES + 63) / 64;         // 313

    // ---------------- layer 1: x -> h (H=128) ----------------
    for (int v = 0; v < 3; ++v) {
        int j0 = perm[v][0], j1 = perm[v][1], j2 = perm[v][2];
        dim3 g(gemmBlocks, 3);
        // bf16 path: batched MFMA
        gemm_mfma1_kernel<<<g, 256, 0, stream>>>(
            flag,
            (const unsigned short*)d_in[j0], (const unsigned short*)d_in[j1],
            (const unsigned short*)d_in[j2],
            Wt1 + (long)v * 3 * H_DIM * F_DIM, Eb, N_NODES);
        // fp32 path: batched split-bf16 MFMA
        gemm_mfma1f_kernel<<<g, 256, 0, stream>>>(
            flag,
            (const float*)d_in[j0], (const float*)d_in[j1], (const float*)d_in[j2],
            W1h + (long)v * 3 * H_DIM * F_DIM, W1l + (long)v * 3 * H_DIM * F_DIM,
            ws + P_E, N_NODES);

        spmm_bf16_kernel<128, false, true><<<N_NODES / 4, 256, 0, stream>>>(
            flag, rp[j0], ed[j0], rp[j1], ed[j1], rp[j2], ed[j2],
            Eb, Eb + (long)N_NODES * H_DIM, Eb + 2L * N_NODES * H_DIM,
            ws + P_WV1 + v * 3, ws + P_B1 + v * H_DIM,
            Hb + (long)v * N_NODES * H_DIM);
        spmm_f32_kernel<2, false><<<N_NODES / 4, 256, 0, stream>>>(
            flag, rp[j0], ed[j0], rp[j1], ed[j1], rp[j2], ed[j2],
            ws + P_E, ws + P_E + (long)N_NODES * H_DIM, ws + P_E + 2L * N_NODES * H_DIM,
            ws + P_WV1 + v * 3, ws + P_B1 + v * H_DIM,
            ws + P_H + (long)v * N_NODES * H_DIM);
    }

    // fp32-path split W2 (into dead L1-Er space; L2 Er uses only first 3.84M)
    unsigned short* W2h = (unsigned short*)(ws + P_W2H);
    unsigned short* W2l = (unsigned short*)(ws + P_W2L);
    {
        dim3 g2(H_DIM / 64, C_DIM / 64, 9);
        split_w_kernel<<<g2, 256, 0, stream>>>(flag, (const float*)d_in[15],
                                               W2h, W2l, H_DIM, C_DIM);
    }

    // ---------------- layer 2: h -> y (C=64), accumulate ysum ----------------
    for (int v = 0; v < 3; ++v) {
        int j0 = perm[v][0], j1 = perm[v][1], j2 = perm[v][2];
        dim3 g(gemmBlocks, 3);
        // bf16 path: batched MFMA
        gemm_mfma2_kernel<<<g, 256, 0, stream>>>(
            flag,
            Hb + (long)j0 * N_NODES * H_DIM, Hb + (long)j1 * N_NODES * H_DIM,
            Hb + (long)j2 * N_NODES * H_DIM,
            Wt2 + (long)v * 3 * C_DIM * H_DIM, Eb, N_NODES);
        // fp32 path: batched split-bf16 MFMA
        gemm_mfma2f_kernel<<<g, 256, 0, stream>>>(
            flag,
            ws + P_H + (long)j0 * N_NODES * H_DIM,
            ws + P_H + (long)j1 * N_NODES * H_DIM,
            ws + P_H + (long)j2 * N_NODES * H_DIM,
            W2h + (long)v * 3 * C_DIM * H_DIM, W2l + (long)v * 3 * C_DIM * H_DIM,
            ws + P_E, N_NODES);

        if (v == 0) {
            spmm_bf16_kernel<64, false, false><<<N_NODES / 8, 256, 0, stream>>>(
                flag, rp[j0], ed[j0], rp[j1], ed[j1], rp[j2], ed[j2],
                Eb, Eb + (long)N_NODES * C_DIM, Eb + 2L * N_NODES * C_DIM,
                ws + P_WV2 + v * 3, ws + P_B2 + v * C_DIM, ws + P_YSUM);
            spmm_f32_kernel<1, false><<<N_NODES / 4, 256, 0, stream>>>(
                flag, rp[j0], ed[j0], rp[j1], ed[j1], rp[j2], ed[j2],
                ws + P_E, ws + P_E + (long)N_NODES * C_DIM, ws + P_E + 2L * N_NODES * C_DIM,
                ws + P_WV2 + v * 3, ws + P_B2 + v * C_DIM, ws + P_YSUM);
        } else {
            spmm_bf16_kernel<64, true, false><<<N_NODES / 8, 256, 0, stream>>>(
                flag, rp[j0], ed[j0], rp[j1], ed[j1], rp[j2], ed[j2],
                Eb, Eb + (long)N_NODES * C_DIM, Eb + 2L * N_NODES * C_DIM,
                ws + P_WV2 + v * 3, ws + P_B2 + v * C_DIM, ws + P_YSUM);
            spmm_f32_kernel<1, true><<<N_NODES / 4, 256, 0, stream>>>(
                flag, rp[j0], ed[j0], rp[j1], ed[j1], rp[j2], ed[j2],
                ws + P_E, ws + P_E + (long)N_NODES * C_DIM, ws + P_E + 2L * N_NODES * C_DIM,
                ws + P_WV2 + v * 3, ws + P_B2 + v * C_DIM, ws + P_YSUM);
        }
    }

    final_kernel<__hip_bfloat16><<<(out_size + 255) / 256, 256, 0, stream>>>(
        flag, 0, ws + P_YSUM, (__hip_bfloat16*)d_out, out_size);
    final_kernel<float><<<(out_size + 255) / 256, 256, 0, stream>>>(
        flag, 1, ws + P_YSUM, (float*)d_out, out_size);
}

// Round 10
// 899.561 us; speedup vs baseline: 1.4290x; 1.2034x over previous
//
#include <hip/hip_runtime.h>
#include <hip/hip_bf16.h>

// Problem constants (from the reference)
#define N_NODES 20000
#define F_DIM   512
#define H_DIM   128
#define C_DIM   64
#define E_EDGES 640000

// ---------------- workspace layout (float offsets from d_ws) ----------------
// flag: int at word 0 (1 = inputs are f32, 0 = inputs are bf16)
#define P_WV1   64                      // 9 floats
#define P_B1    80                      // 384 floats
#define P_WV2   464                     // 9
#define P_B2    480                     // 192 -> ends 672
#define P_E     1024                    // Er tables, bf16, BOTH paths (<=3.84M words)
#define P_H     (P_E + 3*N_NODES*H_DIM) // h tables, bf16, BOTH paths
#define P_YSUM  (P_H + 3*N_NODES*H_DIM) // N*C f32 (both paths)
// CSR region: 3 adjacencies, each {rowptr[20032 ints], packed edges int2[E]}
#define RP_SZ      20032
#define CSR_STRIDE (RP_SZ + 2*E_EDGES)          // in 4-byte words (unchanged)
#define P_CSR   (P_YSUM + N_NODES*C_DIM)
#define P_CUR   (P_CSR + 3*CSR_STRIDE)          // legacy scratch (unused now)
// pre-transposed weights inside P_E slack (bf16 Eb tables use <= 3.84M of the
// 7.68M-word region):
#define P_WT1   (P_E + 4000000)                 // flag0: 9*128*512 bf16 = 294912 words
#define P_WT2   (P_E + 4300000)                 // BOTH paths: 9*64*128 bf16 = 36864 words
// fp32-path split W1 (hi/lo bf16, k-major) in P_YSUM (free until layer-2):
#define P_W1H   (P_YSUM)
#define P_W1L   (P_YSUM + 294912)
// CSR-build scratch: (src,bucket) histogram->scan (in place) + cursors + bsums.
// 2 x 3 x 160000 + 3 x 640 ints < 1.28M words, in P_YSUM, dead during build.
#define NBUCK       8                           // 5 used (dst>>12, dst<20000)
#define BUCK_SHIFT  12
#define B2_STRIDE   (N_NODES * NBUCK)           // 160000 = 625 * 256 exactly
#define NBLK_SCAN   625
#define BSUM_STRIDE 640
// total footprint unchanged at ~20.56M words = 82.2 MB (harness-verified)

typedef __attribute__((ext_vector_type(8))) unsigned short u16x8;
typedef __attribute__((ext_vector_type(8))) __bf16 bf16x8;
typedef __attribute__((ext_vector_type(4))) float f32x4;

__device__ inline float cvt(float x) { return x; }
__device__ inline float cvt(__hip_bfloat16 x) { return __bfloat162float(x); }

__device__ inline void store_out(float v, float* p) { *p = v; }
__device__ inline void store_out(float v, __hip_bfloat16* p) { *p = __float2bfloat16(v); }

__device__ inline unsigned short f2bf_bits(float x) {
    __hip_bfloat16 b = __float2bfloat16(x);
    return *(unsigned short*)&b;
}
// split fp32 -> (hi, lo) bf16 pair: x ~= hi + lo, |x-(hi+lo)| ~ 2^-17 |x|
__device__ inline void splitbf(float x, unsigned short& h, unsigned short& l) {
    h = f2bf_bits(x);
    float hf = __uint_as_float(((unsigned int)h) << 16);
    l = f2bf_bits(x - hf);
}

// ---------------- dtype probe ----------------
__global__ void detect_kernel(const unsigned short* __restrict__ x, int* flag) {
    __shared__ int cnt;
    if (threadIdx.x == 0) cnt = 0;
    __syncthreads();
    int c = 0;
    for (int i = threadIdx.x; i < 4096; i += 256) {
        int ex = (x[i] >> 7) & 0xff;
        if (ex >= 140) c++;
    }
    atomicAdd(&cnt, c);
    __syncthreads();
    if (threadIdx.x == 0) *flag = (cnt > 64) ? 1 : 0;
}

// Convert the small params (wv1,b1,wv2,b2) to fp32 in ws.
__global__ void prep_kernel(const int* __restrict__ flag,
                            const void* wv1, const void* b1,
                            const void* wv2, const void* b2, float* ws) {
    bool f32 = (*flag == 1);
    int t = threadIdx.x;
    auto get = [&](const void* p, int i) -> float {
        return f32 ? ((const float*)p)[i]
                   : __bfloat162float(((const __hip_bfloat16*)p)[i]);
    };
    if (t < 9) ws[P_WV1 + t] = get(wv1, t);
    if (t < 9) ws[P_WV2 + t] = get(wv2, t);
    for (int i = t; i < 3*H_DIM; i += 256) ws[P_B1 + i] = get(b1, i);
    for (int i = t; i < 3*C_DIM; i += 256) ws[P_B2 + i] = get(b2, i);
}

// ---------------- CSR build (batched, dst-bucket-ordered rows) --------------
__global__ __launch_bounds__(256)
void hist2_kernel(const int* __restrict__ s0, const int* __restrict__ d0,
                  const int* __restrict__ s1, const int* __restrict__ d1,
                  const int* __restrict__ s2, const int* __restrict__ d2,
                  int* __restrict__ deg2) {
    int e = blockIdx.x * 256 + threadIdx.x;
    if (e >= E_EDGES) return;
    const int z = blockIdx.y;
    const int* src = (z == 0) ? s0 : (z == 1) ? s1 : s2;
    const int* dst = (z == 0) ? d0 : (z == 1) ? d1 : d2;
    int idx = src[e] * NBUCK + (dst[e] >> BUCK_SHIFT);
    atomicAdd(&deg2[z * B2_STRIDE + idx], 1);
}

// Parallel 3-phase exclusive scan over deg2.
__global__ __launch_bounds__(256)
void scanA_kernel(int* __restrict__ deg2, int* __restrict__ bsum) {
    __shared__ int s[256];
    const int z = blockIdx.y;
    int* d = deg2 + z * B2_STRIDE;
    const int t = threadIdx.x;
    const int i = blockIdx.x * 256 + t;
    int v = d[i];
    s[t] = v;
    __syncthreads();
    for (int off = 1; off < 256; off <<= 1) {
        int u = (t >= off) ? s[t - off] : 0;
        __syncthreads();
        s[t] += u;
        __syncthreads();
    }
    d[i] = s[t] - v;
    if (t == 255) bsum[z * BSUM_STRIDE + blockIdx.x] = s[255];
}

__global__ __launch_bounds__(256)
void scanB_kernel(int* __restrict__ bsum) {
    __shared__ int sums[256];
    int* b = bsum + blockIdx.x * BSUM_STRIDE;
    const int t = threadIdx.x;
    int beg = t * 3, end = beg + 3; if (end > NBLK_SCAN) end = NBLK_SCAN;
    int s = 0;
    for (int i = beg; i < end && i < NBLK_SCAN; ++i) s += b[i];
    sums[t] = s;
    __syncthreads();
    for (int off = 1; off < 256; off <<= 1) {
        int u = (t >= off) ? sums[t - off] : 0;
        __syncthreads();
        sums[t] += u;
        __syncthreads();
    }
    int run = sums[t] - s;
    for (int i = beg; i < end && i < NBLK_SCAN; ++i) { int v = b[i]; b[i] = run; run += v; }
}

__global__ __launch_bounds__(256)
void scanC_kernel(int* __restrict__ deg2, const int* __restrict__ bsum,
                  int* __restrict__ rpBase) {
    const int z = blockIdx.y;
    int* d = deg2 + z * B2_STRIDE;
    int* rowptr = rpBase + (long)z * CSR_STRIDE;
    const int i = blockIdx.x * 256 + threadIdx.x;
    int v = d[i] + bsum[z * BSUM_STRIDE + blockIdx.x];
    d[i] = v;
    if ((i & (NBUCK - 1)) == 0) rowptr[i >> 3] = v;
    if (i == 0) rowptr[N_NODES] = E_EDGES;
}

__global__ __launch_bounds__(256)
void fill3_kernel(const int* __restrict__ flag,
                  const int* __restrict__ s0, const int* __restrict__ d0,
                  const void* __restrict__ v0,
                  const int* __restrict__ s1, const int* __restrict__ d1,
                  const void* __restrict__ v1,
                  const int* __restrict__ s2, const int* __restrict__ d2,
                  const void* __restrict__ v2,
                  const int* __restrict__ deg2, int* __restrict__ cur2,
                  int* __restrict__ rpBase) {
    int e = blockIdx.x * 256 + threadIdx.x;
    if (e >= E_EDGES) return;
    const int z = blockIdx.y;
    const int* src = (z == 0) ? s0 : (z == 1) ? s1 : s2;
    const int* dst = (z == 0) ? d0 : (z == 1) ? d1 : d2;
    const void* val = (z == 0) ? v0 : (z == 1) ? v1 : v2;
    float v = (*flag == 1) ? ((const float*)val)[e]
                           : __bfloat162float(((const __hip_bfloat16*)val)[e]);
    int d = dst[e];
    int idx = z * B2_STRIDE + src[e] * NBUCK + (d >> BUCK_SHIFT);
    int pos = deg2[idx] + atomicAdd(&cur2[idx], 1);
    int2* ed = (int2*)(rpBase + (long)z * CSR_STRIDE + RP_SZ);
    ed[pos] = make_int2(d, __float_as_int(v));
}

// ---------------- weight transpose, bf16 source (flag0, Wt1) ----------------
// W [z][K][HO] bf16  ->  Wt [z][HO][K] bf16
__global__ __launch_bounds__(256)
void transpose_w_kernel(const int* __restrict__ flag,
                        const void* __restrict__ Wsrc,
                        unsigned short* __restrict__ Wt, int K, int HO) {
    if (*flag != 0) return;
    __shared__ unsigned short T[64][80];
    const unsigned short* W = (const unsigned short*)Wsrc + (long)blockIdx.z * K * HO;
    unsigned short* O = Wt + (long)blockIdx.z * HO * K;
    const int k0 = blockIdx.x * 64, n0 = blockIdx.y * 64;
    const int t = threadIdx.x;
    const int rr = t >> 3, cc = (t & 7) * 8;
    #pragma unroll
    for (int i = 0; i < 2; ++i) {
        int k = rr + i * 32;
        *(u16x8*)&T[k][cc] = *(const u16x8*)&W[(long)(k0 + k) * HO + n0 + cc];
    }
    __syncthreads();
    #pragma unroll
    for (int i = 0; i < 2; ++i) {
        int nn = rr + i * 32;
        u16x8 v;
        #pragma unroll
        for (int j = 0; j < 8; ++j) v[j] = T[cc + j][nn];
        *(u16x8*)&O[(long)(n0 + nn) * K + k0 + cc] = v;
    }
}

// ---------------- Wt2 transpose, flag-decoded source (BOTH paths) -----------
// W2 [z][128][64] (f32 or bf16 per flag) -> Wt2 [z][64][128] bf16. Tiny.
__global__ __launch_bounds__(256)
void transpose_wt2_kernel(const int* __restrict__ flag,
                          const void* __restrict__ Wsrc,
                          unsigned short* __restrict__ Wt) {
    const bool f32 = (*flag == 1);
    const int z = blockIdx.x;
    const long base = (long)z * H_DIM * C_DIM;
    unsigned short* O = Wt + (long)z * C_DIM * H_DIM;
    for (int idx = threadIdx.x; idx < H_DIM * C_DIM; idx += 256) {
        int k = idx >> 6, n = idx & 63;         // k in [0,128), n in [0,64)
        float v = f32 ? ((const float*)Wsrc)[base + idx]
                      : __bfloat162float(((const __hip_bfloat16*)Wsrc)[base + idx]);
        O[(long)n * H_DIM + k] = f2bf_bits(v);
    }
}

// ---------------- W1 transpose + hi/lo split (fp32 path) ----------------
__global__ __launch_bounds__(256)
void split_w_kernel(const int* __restrict__ flag,
                    const float* __restrict__ Wsrc,
                    unsigned short* __restrict__ Wh,
                    unsigned short* __restrict__ Wl, int K, int HO) {
    if (*flag != 1) return;
    __shared__ float T[64][68];
    const float* W = Wsrc + (long)blockIdx.z * K * HO;
    unsigned short* Oh = Wh + (long)blockIdx.z * HO * K;
    unsigned short* Ol = Wl + (long)blockIdx.z * HO * K;
    const int k0 = blockIdx.x * 64, n0 = blockIdx.y * 64;
    const int t = threadIdx.x;
    #pragma unroll
    for (int i = 0; i < 16; ++i) {
        int idx = t + i * 256;
        int r = idx >> 6, c = idx & 63;
        T[r][c] = W[(long)(k0 + r) * HO + n0 + c];
    }
    __syncthreads();
    #pragma unroll
    for (int i = 0; i < 16; ++i) {
        int idx = t + i * 256;
        int nn = idx >> 6, kk = idx & 63;
        unsigned short h, l;
        splitbf(T[kk][nn], h, l);
        Oh[(long)(n0 + nn) * K + k0 + kk] = h;
        Ol[(long)(n0 + nn) * K + k0 + kk] = l;
    }
}

// ---------------- MFMA GEMM layer 1 (bf16 path): out[N,128]bf16 -------------
#define SWZ(r, kb) (((r) << 7) + ((kb) ^ (((r) & 7) << 4)))

__global__ __launch_bounds__(256)
void gemm_mfma1_kernel(const int* __restrict__ flag,
                       const unsigned short* __restrict__ x0,
                       const unsigned short* __restrict__ x1,
                       const unsigned short* __restrict__ x2,
                       const unsigned short* __restrict__ WtBase,
                       unsigned short* __restrict__ outBase, int n) {
    if (*flag != 0) return;
    const int role = blockIdx.y;
    const unsigned short* X = (role == 0) ? x0 : (role == 1) ? x1 : x2;
    const unsigned short* Wt = WtBase + (long)role * H_DIM * F_DIM;
    unsigned short* out = outBase + (long)role * N_NODES * H_DIM;
    __shared__ __align__(16) unsigned short As[64 * 64];
    __shared__ __align__(16) unsigned short Bs[128 * 64];
    const int t = threadIdx.x;
    const int lane = t & 63;
    const int wave = t >> 6;
    const int wm = wave & 1, wn = wave >> 1;
    const int row0 = blockIdx.x * 64;
    const int rl = lane & 15;
    const int kq = lane >> 4;
    const int sr = t >> 3;
    const int sc = (t & 7) * 8;
    f32x4 acc[2][4] = {};
    for (int k0 = 0; k0 < F_DIM; k0 += 64) {
        #pragma unroll
        for (int i = 0; i < 2; ++i) {
            int r = i * 32 + sr;
            int gr = row0 + r; if (gr >= n) gr = n - 1;
            u16x8 v = *(const u16x8*)&X[(long)gr * F_DIM + k0 + sc];
            *(u16x8*)((char*)As + SWZ(r, sc * 2)) = v;
        }
        #pragma unroll
        for (int i = 0; i < 4; ++i) {
            int r = i * 32 + sr;
            u16x8 v = *(const u16x8*)&Wt[(long)r * F_DIM + k0 + sc];
            *(u16x8*)((char*)Bs + SWZ(r, sc * 2)) = v;
        }
        __syncthreads();
        #pragma unroll
        for (int s = 0; s < 2; ++s) {
            const int kb = s * 64 + kq * 16;
            bf16x8 af[2], bfr[4];
            #pragma unroll
            for (int mi = 0; mi < 2; ++mi) {
                int r = wm * 32 + mi * 16 + rl;
                af[mi] = *(const bf16x8*)((const char*)As + SWZ(r, kb));
            }
            #pragma unroll
            for (int ni = 0; ni < 4; ++ni) {
                int r = wn * 64 + ni * 16 + rl;
                bfr[ni] = *(const bf16x8*)((const char*)Bs + SWZ(r, kb));
            }
            #pragma unroll
            for (int mi = 0; mi < 2; ++mi)
                #pragma unroll
                for (int ni = 0; ni < 4; ++ni)
                    acc[mi][ni] = __builtin_amdgcn_mfma_f32_16x16x32_bf16(
                        af[mi], bfr[ni], acc[mi][ni], 0, 0, 0);
        }
        __syncthreads();
    }
    #pragma unroll
    for (int mi = 0; mi < 2; ++mi) {
        #pragma unroll
        for (int q = 0; q < 4; ++q) {
            int row = row0 + wm * 32 + mi * 16 + kq * 4 + q;
            if (row < n) {
                #pragma unroll
                for (int ni = 0; ni < 4; ++ni) {
                    int col = wn * 64 + ni * 16 + rl;
                    out[(long)row * H_DIM + col] = f2bf_bits(acc[mi][ni][q]);
                }
            }
        }
    }
}

// ---------------- MFMA GEMM layer 1 (fp32 path, split-bf16 3-product) -------
// Output now bf16 (per-element ~2^-9 rounding; GEMM itself ~2^-17 accurate).
__global__ __launch_bounds__(256)
void gemm_mfma1f_kernel(const int* __restrict__ flag,
                        const float* __restrict__ x0,
                        const float* __restrict__ x1,
                        const float* __restrict__ x2,
                        const unsigned short* __restrict__ WhBase,
                        const unsigned short* __restrict__ WlBase,
                        unsigned short* __restrict__ outBase, int n) {
    if (*flag != 1) return;
    const int role = blockIdx.y;
    const float* X = (role == 0) ? x0 : (role == 1) ? x1 : x2;
    const unsigned short* Wh = WhBase + (long)role * H_DIM * F_DIM;
    const unsigned short* Wl = WlBase + (long)role * H_DIM * F_DIM;
    unsigned short* out = outBase + (long)role * N_NODES * H_DIM;
    __shared__ __align__(16) unsigned short Ash[64 * 64];
    __shared__ __align__(16) unsigned short Asl[64 * 64];
    __shared__ __align__(16) unsigned short Bsh[128 * 64];
    __shared__ __align__(16) unsigned short Bsl[128 * 64];
    const int t = threadIdx.x;
    const int lane = t & 63;
    const int wave = t >> 6;
    const int wm = wave & 1, wn = wave >> 1;
    const int row0 = blockIdx.x * 64;
    const int rl = lane & 15;
    const int kq = lane >> 4;
    const int sr = t >> 3;
    const int sc = (t & 7) * 8;
    f32x4 acc[2][4] = {};
    for (int k0 = 0; k0 < F_DIM; k0 += 64) {
        #pragma unroll
        for (int i = 0; i < 2; ++i) {
            int r = i * 32 + sr;
            int gr = row0 + r; if (gr >= n) gr = n - 1;
            float4 v0 = *(const float4*)&X[(long)gr * F_DIM + k0 + sc];
            float4 v1 = *(const float4*)&X[(long)gr * F_DIM + k0 + sc + 4];
            float xs[8] = {v0.x, v0.y, v0.z, v0.w, v1.x, v1.y, v1.z, v1.w};
            u16x8 hi, lo;
            #pragma unroll
            for (int j = 0; j < 8; ++j) { unsigned short h, l; splitbf(xs[j], h, l); hi[j] = h; lo[j] = l; }
            *(u16x8*)((char*)Ash + SWZ(r, sc * 2)) = hi;
            *(u16x8*)((char*)Asl + SWZ(r, sc * 2)) = lo;
        }
        #pragma unroll
        for (int i = 0; i < 4; ++i) {
            int r = i * 32 + sr;
            u16x8 vh = *(const u16x8*)&Wh[(long)r * F_DIM + k0 + sc];
            u16x8 vl = *(const u16x8*)&Wl[(long)r * F_DIM + k0 + sc];
            *(u16x8*)((char*)Bsh + SWZ(r, sc * 2)) = vh;
            *(u16x8*)((char*)Bsl + SWZ(r, sc * 2)) = vl;
        }
        __syncthreads();
        #pragma unroll
        for (int s = 0; s < 2; ++s) {
            const int kb = s * 64 + kq * 16;
            bf16x8 ah[2], al[2], bh[4], bl[4];
            #pragma unroll
            for (int mi = 0; mi < 2; ++mi) {
                int r = wm * 32 + mi * 16 + rl;
                ah[mi] = *(const bf16x8*)((const char*)Ash + SWZ(r, kb));
                al[mi] = *(const bf16x8*)((const char*)Asl + SWZ(r, kb));
            }
            #pragma unroll
            for (int ni = 0; ni < 4; ++ni) {
                int r = wn * 64 + ni * 16 + rl;
                bh[ni] = *(const bf16x8*)((const char*)Bsh + SWZ(r, kb));
                bl[ni] = *(const bf16x8*)((const char*)Bsl + SWZ(r, kb));
            }
            #pragma unroll
            for (int mi = 0; mi < 2; ++mi)
                #pragma unroll
                for (int ni = 0; ni < 4; ++ni) {
                    acc[mi][ni] = __builtin_amdgcn_mfma_f32_16x16x32_bf16(
                        ah[mi], bh[ni], acc[mi][ni], 0, 0, 0);
                    acc[mi][ni] = __builtin_amdgcn_mfma_f32_16x16x32_bf16(
                        ah[mi], bl[ni], acc[mi][ni], 0, 0, 0);
                    acc[mi][ni] = __builtin_amdgcn_mfma_f32_16x16x32_bf16(
                        al[mi], bh[ni], acc[mi][ni], 0, 0, 0);
                }
        }
        __syncthreads();
    }
    #pragma unroll
    for (int mi = 0; mi < 2; ++mi) {
        #pragma unroll
        for (int q = 0; q < 4; ++q) {
            int row = row0 + wm * 32 + mi * 16 + kq * 4 + q;
            if (row < n) {
                #pragma unroll
                for (int ni = 0; ni < 4; ++ni) {
                    int col = wn * 64 + ni * 16 + rl;
                    out[(long)row * H_DIM + col] = f2bf_bits(acc[mi][ni][q]);
                }
            }
        }
    }
}

// ---------------- MFMA GEMM layer 2 (BOTH paths): out[N,64]bf16 -------------
#define SWZ2(r, kb) (((r) << 8) + ((kb) ^ (((r) & 7) << 4)))

__global__ __launch_bounds__(256)
void gemm_mfma2_kernel(const unsigned short* __restrict__ h0,
                       const unsigned short* __restrict__ h1,
                       const unsigned short* __restrict__ h2,
                       const unsigned short* __restrict__ WtBase,
                       unsigned short* __restrict__ outBase, int n) {
    const int role = blockIdx.y;
    const unsigned short* X = (role == 0) ? h0 : (role == 1) ? h1 : h2;
    const unsigned short* Wt = WtBase + (long)role * C_DIM * H_DIM;
    unsigned short* out = outBase + (long)role * N_NODES * C_DIM;
    __shared__ __align__(16) unsigned short As[64 * 128];
    __shared__ __align__(16) unsigned short Bs[64 * 128];
    const int t = threadIdx.x;
    const int lane = t & 63;
    const int wave = t >> 6;
    const int wm = wave & 1, wn = wave >> 1;
    const int row0 = blockIdx.x * 64;
    const int rl = lane & 15;
    const int kq = lane >> 4;
    #pragma unroll
    for (int i = 0; i < 4; ++i) {
        int e = t + i * 256;
        int r = e >> 4, c8 = e & 15;
        int gr = row0 + r; if (gr >= n) gr = n - 1;
        u16x8 va = *(const u16x8*)&X[(long)gr * H_DIM + c8 * 8];
        *(u16x8*)((char*)As + SWZ2(r, c8 * 16)) = va;
        u16x8 vb = *(const u16x8*)&Wt[(long)r * H_DIM + c8 * 8];
        *(u16x8*)((char*)Bs + SWZ2(r, c8 * 16)) = vb;
    }
    __syncthreads();
    f32x4 acc[2][2] = {};
    #pragma unroll
    for (int s = 0; s < 4; ++s) {
        const int kb = s * 64 + kq * 16;
        bf16x8 af[2], bfr[2];
        #pragma unroll
        for (int mi = 0; mi < 2; ++mi) {
            int r = wm * 32 + mi * 16 + rl;
            af[mi] = *(const bf16x8*)((const char*)As + SWZ2(r, kb));
        }
        #pragma unroll
        for (int ni = 0; ni < 2; ++ni) {
            int r = wn * 32 + ni * 16 + rl;
            bfr[ni] = *(const bf16x8*)((const char*)Bs + SWZ2(r, kb));
        }
        #pragma unroll
        for (int mi = 0; mi < 2; ++mi)
            #pragma unroll
            for (int ni = 0; ni < 2; ++ni)
                acc[mi][ni] = __builtin_amdgcn_mfma_f32_16x16x32_bf16(
                    af[mi], bfr[ni], acc[mi][ni], 0, 0, 0);
    }
    #pragma unroll
    for (int mi = 0; mi < 2; ++mi) {
        #pragma unroll
        for (int q = 0; q < 4; ++q) {
            int row = row0 + wm * 32 + mi * 16 + kq * 4 + q;
            if (row < n) {
                #pragma unroll
                for (int ni = 0; ni < 2; ++ni) {
                    int col = wn * 32 + ni * 16 + rl;
                    out[(long)row * C_DIM + col] = f2bf_bits(acc[mi][ni][q]);
                }
            }
        }
    }
}

// ---------------- fused CSR SpMM, bf16 tables (BOTH paths), packed edges ----
// want < 0: unguarded (runs for both dtype cases).
template <int HO, bool ACCUM, bool OUT_BF16>
__global__ __launch_bounds__(256)
void spmm_bf16_kernel(const int* __restrict__ flag, int want,
                      const int* __restrict__ rp0, const int2* __restrict__ ed0,
                      const int* __restrict__ rp1, const int2* __restrict__ ed1,
                      const int* __restrict__ rp2, const int2* __restrict__ ed2,
                      const unsigned short* __restrict__ Et0,
                      const unsigned short* __restrict__ Et1,
                      const unsigned short* __restrict__ Et2,
                      const float* __restrict__ wvp, const float* __restrict__ bias,
                      void* __restrict__ outp) {
    if (want >= 0 && *flag != want) return;
    constexpr int NL = HO / 2;                  // lanes per node
    constexpr int NPW = 64 / NL;                // nodes per wave
    const int t = threadIdx.x;
    const int lane = t & 63;
    const int li = lane % NL;
    const int node = blockIdx.x * (4 * NPW) + (t >> 6) * NPW + lane / NL;
    const int fl = li * 2;
    float a0 = 0.f, a1 = 0.f;

    const int*  rps[3] = {rp0, rp1, rp2};
    const int2* eds[3] = {ed0, ed1, ed2};
    const unsigned int* Ets[3] = {(const unsigned int*)Et0,
                                  (const unsigned int*)Et1,
                                  (const unsigned int*)Et2};
    #pragma unroll
    for (int r = 0; r < 3; ++r) {
        const float s = 1.01f * wvp[r];
        const int2* ed = eds[r];
        const unsigned int* Et = Ets[r] + li;   // word index: d*NL + li
        int e = rps[r][node];
        const int end = rps[r][node + 1];
        for (; e + 4 <= end; e += 4) {
            int2 E0 = ed[e], E1 = ed[e + 1], E2 = ed[e + 2], E3 = ed[e + 3];
            float v0 = s * __int_as_float(E0.y), v1 = s * __int_as_float(E1.y);
            float v2 = s * __int_as_float(E2.y), v3 = s * __int_as_float(E3.y);
            unsigned int w0 = Et[(long)E0.x * NL];
            unsigned int w1 = Et[(long)E1.x * NL];
            unsigned int w2 = Et[(long)E2.x * NL];
            unsigned int w3 = Et[(long)E3.x * NL];
            a0 += v0 * __uint_as_float(w0 << 16);
            a1 += v0 * __uint_as_float(w0 & 0xffff0000u);
            a0 += v1 * __uint_as_float(w1 << 16);
            a1 += v1 * __uint_as_float(w1 & 0xffff0000u);
            a0 += v2 * __uint_as_float(w2 << 16);
            a1 += v2 * __uint_as_float(w2 & 0xffff0000u);
            a0 += v3 * __uint_as_float(w3 << 16);
            a1 += v3 * __uint_as_float(w3 & 0xffff0000u);
        }
        for (; e < end; ++e) {
            int2 E0 = ed[e];
            float v0 = s * __int_as_float(E0.y);
            unsigned int w0 = Et[(long)E0.x * NL];
            a0 += v0 * __uint_as_float(w0 << 16);
            a1 += v0 * __uint_as_float(w0 & 0xffff0000u);
        }
    }
    unsigned int ws0 = ((const unsigned int*)Et0)[(long)node * NL + li];
    float x0 = __uint_as_float(ws0 << 16)        + a0 + bias[fl];
    float x1 = __uint_as_float(ws0 & 0xffff0000u) + a1 + bias[fl + 1];
    x0 = x0 > 0.f ? x0 : 0.f;
    x1 = x1 > 0.f ? x1 : 0.f;
    if (OUT_BF16) {
        unsigned int packed = ((unsigned int)f2bf_bits(x1) << 16) | f2bf_bits(x0);
        ((unsigned int*)outp)[(long)node * NL + li] = packed;
    } else {
        float* o = (float*)outp + (long)node * HO + fl;
        if (ACCUM) { o[0] += x0; o[1] += x1; }
        else       { o[0] = x0;  o[1] = x1; }
    }
}

template <typename TOUT>
__global__ __launch_bounds__(256)
void final_kernel(const int* __restrict__ flag, int want,
                  const float* __restrict__ ysum, TOUT* __restrict__ out, int n) {
    if (*flag != want) return;
    int i = blockIdx.x * 256 + threadIdx.x;
    if (i >= n) return;
    store_out(fabsf(ysum[i] * (1.f / 3.f)), &out[i]);
}

extern "C" void kernel_launch(void* const* d_in, const int* in_sizes, int n_in,
                              void* d_out, int out_size, void* d_ws, size_t ws_size,
                              hipStream_t stream) {
    float* ws = (float*)d_ws;
    int* flag = (int*)d_ws;
    static const int perm[3][3] = {{0, 1, 2}, {1, 0, 2}, {2, 0, 1}};

    detect_kernel<<<1, 256, 0, stream>>>((const unsigned short*)d_in[0], flag);
    prep_kernel<<<1, 256, 0, stream>>>(flag, d_in[13], d_in[14], d_in[16], d_in[17], ws);

    // ---------------- CSR build (bucket-ordered; scratch in dead P_YSUM) ----
    int* csrbase = (int*)(ws + P_CSR);
    int* rp[3]; int2* ed[3];
    for (int j = 0; j < 3; ++j) {
        rp[j] = csrbase + (long)j * CSR_STRIDE;
        ed[j] = (int2*)(rp[j] + RP_SZ);
    }
    {
        int* deg2 = (int*)(ws + P_YSUM);                // 3 x 160000
        int* cur2 = deg2 + 3 * B2_STRIDE;               // 3 x 160000
        int* bsum = cur2 + 3 * B2_STRIDE;               // 3 x 640
        hipMemsetAsync(deg2, 0, (size_t)6 * B2_STRIDE * 4, stream);
        dim3 ge((E_EDGES + 255) / 256, 3);
        hist2_kernel<<<ge, 256, 0, stream>>>(
            (const int*)d_in[3], (const int*)d_in[4],
            (const int*)d_in[6], (const int*)d_in[7],
            (const int*)d_in[9], (const int*)d_in[10], deg2);
        dim3 gs(NBLK_SCAN, 3);
        scanA_kernel<<<gs, 256, 0, stream>>>(deg2, bsum);
        scanB_kernel<<<3, 256, 0, stream>>>(bsum);
        scanC_kernel<<<gs, 256, 0, stream>>>(deg2, bsum, csrbase);
        fill3_kernel<<<ge, 256, 0, stream>>>(
            flag,
            (const int*)d_in[3], (const int*)d_in[4], d_in[5],
            (const int*)d_in[6], (const int*)d_in[7], d_in[8],
            (const int*)d_in[9], (const int*)d_in[10], d_in[11],
            deg2, cur2, csrbase);
    }

    // Weight prep: Wt1 bf16 (flag0) | W1 hi/lo split (flag1) | Wt2 both paths
    unsigned short* Wt1 = (unsigned short*)(ws + P_WT1);
    unsigned short* Wt2 = (unsigned short*)(ws + P_WT2);
    unsigned short* W1h = (unsigned short*)(ws + P_W1H);
    unsigned short* W1l = (unsigned short*)(ws + P_W1L);
    {
        dim3 g1(F_DIM / 64, H_DIM / 64, 9);
        transpose_w_kernel<<<g1, 256, 0, stream>>>(flag, d_in[12], Wt1, F_DIM, H_DIM);
        split_w_kernel<<<g1, 256, 0, stream>>>(flag, (const float*)d_in[12],
                                               W1h, W1l, F_DIM, H_DIM);
        transpose_wt2_kernel<<<9, 256, 0, stream>>>(flag, d_in[15], Wt2);
    }

    // bf16 tables (both paths): Er at Eb, h at Hb
    unsigned short* Eb = (unsigned short*)(ws + P_E);
    unsigned short* Hb = (unsigned short*)(ws + P_H);

    const int gemmBlocks = (N_NODES + 63) / 64;         // 313

    // ---------------- layer 1: x -> h (H=128) ----------------
    for (int v = 0; v < 3; ++v) {
        int j0 = perm[v][0], j1 = perm[v][1], j2 = perm[v][2];
        dim3 g(gemmBlocks, 3);
        // bf16 path GEMM (flag0)
        gemm_mfma1_kernel<<<g, 256, 0, stream>>>(
            flag,
            (const unsigned short*)d_in[j0], (const unsigned short*)d_in[j1],
            (const unsigned short*)d_in[j2],
            Wt1 + (long)v * 3 * H_DIM * F_DIM, Eb, N_NODES);
        // fp32 path GEMM (flag1), bf16 output
        gemm_mfma1f_kernel<<<g, 256, 0, stream>>>(
            flag,
            (const float*)d_in[j0], (const float*)d_in[j1], (const float*)d_in[j2],
            W1h + (long)v * 3 * H_DIM * F_DIM, W1l + (long)v * 3 * H_DIM * F_DIM,
            Eb, N_NODES);
        // unified aggregation (both paths): bf16 gather -> bf16 h
        spmm_bf16_kernel<128, false, true><<<N_NODES / 4, 256, 0, stream>>>(
            flag, -1, rp[j0], ed[j0], rp[j1], ed[j1], rp[j2], ed[j2],
            Eb, Eb + (long)N_NODES * H_DIM, Eb + 2L * N_NODES * H_DIM,
            ws + P_WV1 + v * 3, ws + P_B1 + v * H_DIM,
            Hb + (long)v * N_NODES * H_DIM);
    }

    // ---------------- layer 2: h -> y (C=64), accumulate ysum ----------------
    for (int v = 0; v < 3; ++v) {
        int j0 = perm[v][0], j1 = perm[v][1], j2 = perm[v][2];
        dim3 g(gemmBlocks, 3);
        // unified bf16 GEMM (both paths)
        gemm_mfma2_kernel<<<g, 256, 0, stream>>>(
            Hb + (long)j0 * N_NODES * H_DIM, Hb + (long)j1 * N_NODES * H_DIM,
            Hb + (long)j2 * N_NODES * H_DIM,
            Wt2 + (long)v * 3 * C_DIM * H_DIM, Eb, N_NODES);
        // unified aggregation -> fp32 ysum
        if (v == 0)
            spmm_bf16_kernel<64, false, false><<<N_NODES / 8, 256, 0, stream>>>(
                flag, -1, rp[j0], ed[j0], rp[j1], ed[j1], rp[j2], ed[j2],
                Eb, Eb + (long)N_NODES * C_DIM, Eb + 2L * N_NODES * C_DIM,
                ws + P_WV2 + v * 3, ws + P_B2 + v * C_DIM, ws + P_YSUM);
        else
            spmm_bf16_kernel<64, true, false><<<N_NODES / 8, 256, 0, stream>>>(
                flag, -1, rp[j0], ed[j0], rp[j1], ed[j1], rp[j2], ed[j2],
                Eb, Eb + (long)N_NODES * C_DIM, Eb + 2L * N_NODES * C_DIM,
                ws + P_WV2 + v * 3, ws + P_B2 + v * C_DIM, ws + P_YSUM);
    }

    final_kernel<__hip_bfloat16><<<(out_size + 255) / 256, 256, 0, stream>>>(
        flag, 0, ws + P_YSUM, (__hip_bfloat16*)d_out, out_size);
    final_kernel<float><<<(out_size + 255) / 256, 256, 0, stream>>>(
        flag, 1, ws + P_YSUM, (float*)d_out, out_size);
}